// Round 10
// baseline (1071.410 us; speedup 1.0000x reference)
//
#include <hip/hip_runtime.h>
#include <hip/hip_bf16.h>
#include <hip/hip_fp16.h>

// GCN 3-layer + edge-MLP head. R10: bin-block edge-parallel gathers with LDS
// fp32 accumulation (acc[256][F+1], LDS atomics; entries are node-random in a
// bin -> low same-address contention, +1 pad kills bank conflicts). p2 and the
// node-sorted edata are GONE: gathers consume p1b's bin-grouped u64 directly.
//
// Build: bin = dst>>8. p1a per-(bin,block) LDS histogram; s1/s2 scans; p1b LDS
// tile-sort + write-combined flush of u64(src|q<<18|dl<<32|bin<<40).
// pre: per-bin dinv (LDS qsum) + g0 = dinv(.)(x@W1) fp16.
// bgather1: ->g1. bgather2: +dense 8->16 ->g2. bgather3: +dense 16->32 +
// head projection -> pqh fp16. head: out[e] = p[a] + q[b].

#define NB1 768
#define NPB 256
#define MAXBINS 1024
#define TILE 4096
#define QS 16384.0f
#define QINV (1.0f / 16384.0f)

typedef _Float16 h4 __attribute__((ext_vector_type(4)));
typedef _Float16 h8 __attribute__((ext_vector_type(8)));
typedef _Float16 h16 __attribute__((ext_vector_type(16)));

__device__ __forceinline__ float sigmoidf_(float x) {
    return 1.0f / (1.0f + __expf(-x));
}

// ---- P1a: per-(bin,block) histogram via LDS
__global__ void p1a_hist(const int* __restrict__ dst, int* __restrict__ bh,
                         int ne, int nbins, int chunk) {
    __shared__ int h[MAXBINS];
    for (int k = threadIdx.x; k < nbins; k += 256) h[k] = 0;
    __syncthreads();
    int base = blockIdx.x * chunk;
    int end = min(base + chunk, ne);
    for (int e = base + threadIdx.x; e < end; e += 256)
        atomicAdd(&h[dst[e] >> 8], 1);
    __syncthreads();
    for (int k = threadIdx.x; k < nbins; k += 256)
        bh[(size_t)k * NB1 + blockIdx.x] = h[k];
}

// ---- S1: per-bin exclusive scan over NB1 block counts + bin totals
__global__ void s1_scan(int* __restrict__ bh, int* __restrict__ bintot) {
    __shared__ int sums[256];
    constexpr int W = NB1 / 256;
    int* row = bh + (size_t)blockIdx.x * NB1;
    int v[W];
    int s = 0;
#pragma unroll
    for (int j = 0; j < W; ++j) { v[j] = row[threadIdx.x * W + j]; s += v[j]; }
    sums[threadIdx.x] = s;
    __syncthreads();
    for (int o = 1; o < 256; o <<= 1) {
        int t = (threadIdx.x >= o) ? sums[threadIdx.x - o] : 0;
        __syncthreads();
        sums[threadIdx.x] += t;
        __syncthreads();
    }
    int excl = sums[threadIdx.x] - s;
#pragma unroll
    for (int j = 0; j < W; ++j) { row[threadIdx.x * W + j] = excl; excl += v[j]; }
    if (threadIdx.x == 255) bintot[blockIdx.x] = sums[255];
}

// ---- S2: exclusive scan of bin totals -> binbase
__global__ void s2_scan(const int* __restrict__ bintot, int* __restrict__ binbase,
                        int nbins, int ne) {
    __shared__ int tmp[1024];
    int tid = threadIdx.x;
    int v = (tid < nbins) ? bintot[tid] : 0;
    tmp[tid] = v;
    __syncthreads();
    for (int o = 1; o < 1024; o <<= 1) {
        int t = (tid >= o) ? tmp[tid - o] : 0;
        __syncthreads();
        tmp[tid] += t;
        __syncthreads();
    }
    if (tid < nbins) binbase[tid] = tmp[tid] - v;
    if (tid == 0) binbase[nbins] = ne;
}

// ---- P1b: LDS tile-sort + coalesced flush into bin-grouped u64 array
__global__ void p1b_scatter(const int* __restrict__ src, const int* __restrict__ dst,
                            const float* __restrict__ ew, const int* __restrict__ bh,
                            const int* __restrict__ binbase,
                            unsigned long long* __restrict__ b64,
                            int ne, int nbins, int chunk) {
    __shared__ unsigned long long stage[TILE];
    __shared__ int hist[MAXBINS];
    __shared__ int boff[MAXBINS];
    __shared__ int cur[MAXBINS];
    __shared__ int ssum[256];
    constexpr int MPT = TILE / 256;
    for (int k = threadIdx.x; k < nbins; k += 256)
        cur[k] = binbase[k] + bh[(size_t)k * NB1 + blockIdx.x];
    int base = blockIdx.x * chunk;
    int endb = min(base + chunk, ne);
    for (int t0 = base; t0 < endb; t0 += TILE) {
        int cnt = min(TILE, endb - t0);
        for (int k = threadIdx.x; k < nbins; k += 256) hist[k] = 0;
        __syncthreads();
        unsigned long long ent[MPT];
        int m = 0;
        for (int j = threadIdx.x; j < cnt; j += 256) {
            int e = t0 + j;
            int d = dst[e];
            float w = sigmoidf_(ew[e]);
            int q = (int)fminf(w * QS + 0.5f, 16383.0f);
            int b = d >> 8;
            ent[m++] = (unsigned long long)((unsigned)src[e] | ((unsigned)q << 18))
                     | ((unsigned long long)(d & 255) << 32)
                     | ((unsigned long long)b << 40);
            atomicAdd(&hist[b], 1);
        }
        __syncthreads();
        int w0 = threadIdx.x * 4;
        int lv[4];
        int ls = 0;
#pragma unroll
        for (int j = 0; j < 4; ++j) {
            int idx = w0 + j;
            lv[j] = (idx < nbins) ? hist[idx] : 0;
            ls += lv[j];
        }
        ssum[threadIdx.x] = ls;
        __syncthreads();
        for (int o = 1; o < 256; o <<= 1) {
            int t = (threadIdx.x >= o) ? ssum[threadIdx.x - o] : 0;
            __syncthreads();
            ssum[threadIdx.x] += t;
            __syncthreads();
        }
        int excl = ssum[threadIdx.x] - ls;
#pragma unroll
        for (int j = 0; j < 4; ++j) {
            int idx = w0 + j;
            if (idx < nbins) { boff[idx] = excl; excl += lv[j]; }
        }
        __syncthreads();
        for (int k = threadIdx.x; k < nbins; k += 256) hist[k] = 0;
        __syncthreads();
        for (int j = 0; j < m; ++j) {
            int b = (int)(ent[j] >> 40);
            int p = boff[b] + atomicAdd(&hist[b], 1);
            stage[p] = ent[j];
        }
        __syncthreads();
        for (int j = threadIdx.x; j < cnt; j += 256) {
            unsigned long long v = stage[j];
            int b = (int)(v >> 40);
            b64[cur[b] + (j - boff[b])] = v;
        }
        __syncthreads();
        for (int k = threadIdx.x; k < nbins; k += 256) cur[k] += hist[k];
        __syncthreads();
    }
}

// ---- pre: per-bin dinv (LDS qsum) + fused g0 = dinv (.) (x @ W1) fp16
__global__ __launch_bounds__(512) void pre_kernel(
        const unsigned long long* __restrict__ b64, const int* __restrict__ binbase,
        const float* __restrict__ x, const float* __restrict__ W1,
        float* __restrict__ dinv, _Float16* __restrict__ g0, int n) {
    __shared__ unsigned qsum[NPB];
    __shared__ float Ws[56];
    int tid = threadIdx.x;
    if (tid < 56) Ws[tid] = W1[tid];
    if (tid < NPB) qsum[tid] = 0;
    __syncthreads();
    int bin = blockIdx.x;
    int E0 = binbase[bin], E1 = binbase[bin + 1];
    for (int k = E0 + tid; k < E1; k += 512) {
        unsigned long long v = b64[k];
        atomicAdd(&qsum[(int)((v >> 32) & 0xFF)], (unsigned)((v >> 18) & 0x3FFFu));
    }
    __syncthreads();
    if (tid < NPB) {
        int node = bin * NPB + tid;
        if (node < n) {
            float dv = rsqrtf((float)qsum[tid] * QINV + 1.0f);
            dinv[node] = dv;
            float xi[7];
#pragma unroll
            for (int k = 0; k < 7; ++k) xi[k] = x[(size_t)node * 7 + k];
            h8 r;
#pragma unroll
            for (int o = 0; o < 8; ++o) {
                float acc = 0.0f;
#pragma unroll
                for (int k = 0; k < 7; ++k) acc = fmaf(xi[k], Ws[k * 8 + o], acc);
                r[o] = (_Float16)(acc * dv);
            }
            *reinterpret_cast<h8*>(g0 + (size_t)node * 8) = r;
        }
    }
}

// ---- bgather1: LDS-accumulated bin gather (F=8), epilogue bias+relu -> g1
__global__ __launch_bounds__(512) void bgather1(
        const unsigned long long* __restrict__ b64, const int* __restrict__ binbase,
        const _Float16* __restrict__ g, const float* __restrict__ dinv,
        const float* __restrict__ b1, _Float16* __restrict__ out, int n) {
    __shared__ float acc[NPB][9];
    __shared__ float bs[8];
    int tid = threadIdx.x;
    if (tid < 8) bs[tid] = b1[tid];
    int bin = blockIdx.x;
    if (tid < NPB) {
        int node = bin * NPB + tid;
        if (node < n) {
            h8 r = *reinterpret_cast<const h8*>(g + (size_t)node * 8);
#pragma unroll
            for (int j = 0; j < 8; ++j) acc[tid][j] = (float)r[j];
        }
    }
    __syncthreads();
    int E0 = binbase[bin], E1 = binbase[bin + 1];
    for (int k = E0 + tid; k < E1; k += 512) {
        unsigned long long v = b64[k];
        int s = (int)(v & 0x3FFFFu);
        float w = (float)((v >> 18) & 0x3FFFu) * QINV;
        int dl = (int)((v >> 32) & 0xFF);
        h8 r = *reinterpret_cast<const h8*>(g + (size_t)s * 8);
#pragma unroll
        for (int j = 0; j < 8; ++j) atomicAdd(&acc[dl][j], (float)r[j] * w);
    }
    __syncthreads();
    if (tid < NPB) {
        int node = bin * NPB + tid;
        if (node < n) {
            float dv = dinv[node];
            h8 o8;
#pragma unroll
            for (int j = 0; j < 8; ++j)
                o8[j] = (_Float16)(dv * fmaxf(dv * acc[tid][j] + bs[j], 0.0f));
            *reinterpret_cast<h8*>(out + (size_t)node * 8) = o8;
        }
    }
}

// ---- bgather2: LDS gather (F=8) + fused dense 8->16 -> g2
__global__ __launch_bounds__(512) void bgather2(
        const unsigned long long* __restrict__ b64, const int* __restrict__ binbase,
        const _Float16* __restrict__ g, const float* __restrict__ dinv,
        const float* __restrict__ W2, const float* __restrict__ b2,
        _Float16* __restrict__ out, int n) {
    __shared__ float acc[NPB][9];
    __shared__ float Ws[128];
    __shared__ float bs[16];
    int tid = threadIdx.x;
    if (tid < 128) Ws[tid] = W2[tid];
    if (tid < 16) bs[tid] = b2[tid];
    int bin = blockIdx.x;
    if (tid < NPB) {
        int node = bin * NPB + tid;
        if (node < n) {
            h8 r = *reinterpret_cast<const h8*>(g + (size_t)node * 8);
#pragma unroll
            for (int j = 0; j < 8; ++j) acc[tid][j] = (float)r[j];
        }
    }
    __syncthreads();
    int E0 = binbase[bin], E1 = binbase[bin + 1];
    for (int k = E0 + tid; k < E1; k += 512) {
        unsigned long long v = b64[k];
        int s = (int)(v & 0x3FFFFu);
        float w = (float)((v >> 18) & 0x3FFFu) * QINV;
        int dl = (int)((v >> 32) & 0xFF);
        h8 r = *reinterpret_cast<const h8*>(g + (size_t)s * 8);
#pragma unroll
        for (int j = 0; j < 8; ++j) atomicAdd(&acc[dl][j], (float)r[j] * w);
    }
    __syncthreads();
    if (tid < NPB) {
        int node = bin * NPB + tid;
        if (node < n) {
            float dv = dinv[node];
            float raw[8];
#pragma unroll
            for (int j = 0; j < 8; ++j) raw[j] = dv * acc[tid][j];
            h16 o16;
#pragma unroll
            for (int o = 0; o < 16; ++o) {
                float h = bs[o];
#pragma unroll
                for (int k = 0; k < 8; ++k) h = fmaf(raw[k], Ws[k * 16 + o], h);
                o16[o] = (_Float16)(dv * fmaxf(h, 0.0f));
            }
            *reinterpret_cast<h16*>(out + (size_t)node * 16) = o16;
        }
    }
}

// ---- bgather3: LDS gather (F=16) + fused dense 16->32 + head proj -> pqh fp16
__global__ __launch_bounds__(512) void bgather3(
        const unsigned long long* __restrict__ b64, const int* __restrict__ binbase,
        const _Float16* __restrict__ g, const float* __restrict__ dinv,
        const float* __restrict__ W3, const float* __restrict__ b3,
        const float* __restrict__ Wl1, const float* __restrict__ bl1,
        const float* __restrict__ Wl2, const float* __restrict__ bl2,
        _Float16* __restrict__ pqh, int n) {
    __shared__ float acc[NPB][17];
    __shared__ float Ws[512];
    __shared__ float bs[32];
    __shared__ float wfs[192];
    __shared__ float bfs[3];
    int tid = threadIdx.x;
    for (int k = tid; k < 512; k += 512) Ws[k] = W3[k];
    if (tid < 32) bs[tid] = b3[tid];
    if (tid < 192) {
        int f = tid / 3, j = tid % 3;
        float a = 0.0f;
#pragma unroll
        for (int k = 0; k < 4; ++k) a = fmaf(Wl1[f * 4 + k], Wl2[k * 3 + j], a);
        wfs[tid] = a;
    }
    if (tid < 3) {
        float a = bl2[tid];
#pragma unroll
        for (int k = 0; k < 4; ++k) a = fmaf(bl1[k], Wl2[k * 3 + tid], a);
        bfs[tid] = a;
    }
    int bin = blockIdx.x;
    if (tid < NPB) {
        int node = bin * NPB + tid;
        if (node < n) {
            h16 r = *reinterpret_cast<const h16*>(g + (size_t)node * 16);
#pragma unroll
            for (int j = 0; j < 16; ++j) acc[tid][j] = (float)r[j];
        }
    }
    __syncthreads();
    int E0 = binbase[bin], E1 = binbase[bin + 1];
    for (int k = E0 + tid; k < E1; k += 512) {
        unsigned long long v = b64[k];
        int s = (int)(v & 0x3FFFFu);
        float w = (float)((v >> 18) & 0x3FFFu) * QINV;
        int dl = (int)((v >> 32) & 0xFF);
        h16 r = *reinterpret_cast<const h16*>(g + (size_t)s * 16);
#pragma unroll
        for (int j = 0; j < 16; ++j) atomicAdd(&acc[dl][j], (float)r[j] * w);
    }
    __syncthreads();
    if (tid < NPB) {
        int node = bin * NPB + tid;
        if (node < n) {
            float dv = dinv[node];
            float raw[16];
#pragma unroll
            for (int j = 0; j < 16; ++j) raw[j] = dv * acc[tid][j];
            float p0 = bfs[0], p1 = bfs[1], p2 = bfs[2];
            float q0 = 0.0f, q1 = 0.0f, q2 = 0.0f;
#pragma unroll
            for (int o = 0; o < 32; ++o) {
                float h = bs[o];
#pragma unroll
                for (int k = 0; k < 16; ++k) h = fmaf(raw[k], Ws[k * 32 + o], h);
                h = fmaxf(h, 0.0f);
                p0 = fmaf(h, wfs[o * 3 + 0], p0);
                p1 = fmaf(h, wfs[o * 3 + 1], p1);
                p2 = fmaf(h, wfs[o * 3 + 2], p2);
                q0 = fmaf(h, wfs[(32 + o) * 3 + 0], q0);
                q1 = fmaf(h, wfs[(32 + o) * 3 + 1], q1);
                q2 = fmaf(h, wfs[(32 + o) * 3 + 2], q2);
            }
            h8 o8;
            o8[0] = (_Float16)p0; o8[1] = (_Float16)p1;
            o8[2] = (_Float16)p2; o8[3] = (_Float16)0.0f;
            o8[4] = (_Float16)q0; o8[5] = (_Float16)q1;
            o8[6] = (_Float16)q2; o8[7] = (_Float16)0.0f;
            *reinterpret_cast<h8*>(pqh + (size_t)node * 8) = o8;
        }
    }
}

// ---- head: out[e] = p[a] + q[b]   (fp16 pq table, fp32 out)
__global__ void head_kernel(const int* __restrict__ w2b, const _Float16* __restrict__ pqh,
                            float* __restrict__ out, int nw) {
    int e = blockIdx.x * blockDim.x + threadIdx.x;
    if (e >= nw) return;
    int a = w2b[e];
    int b = w2b[(size_t)nw + e];
    h4 P = *reinterpret_cast<const h4*>(pqh + (size_t)a * 8);
    h4 Q = *reinterpret_cast<const h4*>(pqh + (size_t)b * 8 + 4);
    out[(size_t)e * 3 + 0] = (float)P[0] + (float)Q[0];
    out[(size_t)e * 3 + 1] = (float)P[1] + (float)Q[1];
    out[(size_t)e * 3 + 2] = (float)P[2] + (float)Q[2];
}

extern "C" void kernel_launch(void* const* d_in, const int* in_sizes, int n_in,
                              void* d_out, int out_size, void* d_ws, size_t ws_size,
                              hipStream_t stream) {
    const float* x   = (const float*)d_in[0];
    const int* eidx  = (const int*)d_in[1];
    const int* w2b   = (const int*)d_in[2];
    const float* ew  = (const float*)d_in[3];
    const float* W1  = (const float*)d_in[4];
    const float* b1  = (const float*)d_in[5];
    const float* W2  = (const float*)d_in[6];
    const float* b2  = (const float*)d_in[7];
    const float* W3  = (const float*)d_in[8];
    const float* b3  = (const float*)d_in[9];
    const float* Wl1 = (const float*)d_in[10];
    const float* bl1 = (const float*)d_in[11];
    const float* Wl2 = (const float*)d_in[12];
    const float* bl2 = (const float*)d_in[13];
    float* out = (float*)d_out;

    const int n  = in_sizes[0] / 7;   // 200000
    const int ne = in_sizes[1] / 2;   // 4000000
    const int nw = in_sizes[2] / 2;   // 2000000
    const int* src = eidx;
    const int* dst = eidx + ne;

    const int nbins = (n + NPB - 1) / NPB;    // 782
    const int chunk = (ne + NB1 - 1) / NB1;   // 5209

    // ---- workspace layout (4B words); no aliasing ----
    float*     ws      = (float*)d_ws;
    float*     dinv    = ws;                                   // n
    int*       bh      = (int*)(ws + n);                       // nbins*NB1
    int*       bintot  = bh + (size_t)nbins * NB1;             // MAXBINS
    int*       binbase = bintot + MAXBINS;                     // MAXBINS
    unsigned long long* b64 = (unsigned long long*)(binbase + MAXBINS);  // ne u64
    _Float16*  g0      = (_Float16*)(b64 + ne);                // 8n halves
    _Float16*  g1      = g0 + (size_t)n * 8;                   // 8n halves
    _Float16*  g2      = g1 + (size_t)n * 8;                   // 16n halves
    _Float16*  pqh     = g2 + (size_t)n * 16;                  // 8n halves
    // total ~= n + 600K + 2K + 2ne + 20n words ~= 51 MB

    const int Bl = 256;
    auto blks = [&](long long t) { return (int)((t + Bl - 1) / Bl); };

    // 1. CSR-bin build (counting sort; tile-sorted write-combined scatter)
    p1a_hist<<<NB1, Bl, 0, stream>>>(dst, bh, ne, nbins, chunk);
    s1_scan<<<nbins, Bl, 0, stream>>>(bh, bintot);
    s2_scan<<<1, 1024, 0, stream>>>(bintot, binbase, nbins, ne);
    p1b_scatter<<<NB1, Bl, 0, stream>>>(src, dst, ew, bh, binbase, b64, ne, nbins, chunk);

    // 2. dinv + g0
    pre_kernel<<<nbins, 512, 0, stream>>>(b64, binbase, x, W1, dinv, g0, n);

    // 3. three bin-block LDS-accumulated gather layers
    bgather1<<<nbins, 512, 0, stream>>>(b64, binbase, g0, dinv, b1, g1, n);
    bgather2<<<nbins, 512, 0, stream>>>(b64, binbase, g1, dinv, W2, b2, g2, n);
    bgather3<<<nbins, 512, 0, stream>>>(b64, binbase, g2, dinv, W3, b3,
                                        Wl1, bl1, Wl2, bl2, pqh, n);

    // 4. head
    head_kernel<<<blks(nw), Bl, 0, stream>>>(w2b, pqh, out, nw);
}

// Round 11
// 399.118 us; speedup vs baseline: 2.6844x; 2.6844x over previous
//
#include <hip/hip_runtime.h>
#include <hip/hip_bf16.h>
#include <hip/hip_fp16.h>

// GCN 3-layer + edge-MLP head. R11 = R9 (best: 410us) + 8-lanes-per-node
// gathers: 4-feature-split x 2-edge-interleave (halved serial edge chain,
// 2x threads, one extra shfl_xor(4) to merge edge halves).
// R10's LDS-atomic bin gather REGRESSED 2.6x (434us; 16 serial LDS atomics
// per edge) - reverted.
//
// Build: bin = dst>>8. p1a per-(bin,block) LDS histogram; s1/s2 scans; p1b LDS
// tile-sort + write-combined flush of u64(src|q<<18|dl<<32|bin<<40); p2 per-bin
// CSR finalize (node-sorted 4B edata + C + dinv + fused g0 = dinv(.)(x@W1) fp16).
// gathers: g=dinv(.)h fp16 tables, fp32 accum; denses fused into epilogues.
// head: out[e] = p[a] + q[b] from fp16 pq table.

#define NB1 768
#define NPB 256
#define MAXBINS 1024
#define TILE 4096
#define QS 16384.0f
#define QINV (1.0f / 16384.0f)

typedef _Float16 h2 __attribute__((ext_vector_type(2)));
typedef _Float16 h4 __attribute__((ext_vector_type(4)));
typedef _Float16 h8 __attribute__((ext_vector_type(8)));

__device__ __forceinline__ float sigmoidf_(float x) {
    return 1.0f / (1.0f + __expf(-x));
}

// ---- P1a: per-(bin,block) histogram via LDS
__global__ void p1a_hist(const int* __restrict__ dst, int* __restrict__ bh,
                         int ne, int nbins, int chunk) {
    __shared__ int h[MAXBINS];
    for (int k = threadIdx.x; k < nbins; k += 256) h[k] = 0;
    __syncthreads();
    int base = blockIdx.x * chunk;
    int end = min(base + chunk, ne);
    for (int e = base + threadIdx.x; e < end; e += 256)
        atomicAdd(&h[dst[e] >> 8], 1);
    __syncthreads();
    for (int k = threadIdx.x; k < nbins; k += 256)
        bh[(size_t)k * NB1 + blockIdx.x] = h[k];
}

// ---- S1: per-bin exclusive scan over NB1 block counts + bin totals
__global__ void s1_scan(int* __restrict__ bh, int* __restrict__ bintot) {
    __shared__ int sums[256];
    constexpr int W = NB1 / 256;
    int* row = bh + (size_t)blockIdx.x * NB1;
    int v[W];
    int s = 0;
#pragma unroll
    for (int j = 0; j < W; ++j) { v[j] = row[threadIdx.x * W + j]; s += v[j]; }
    sums[threadIdx.x] = s;
    __syncthreads();
    for (int o = 1; o < 256; o <<= 1) {
        int t = (threadIdx.x >= o) ? sums[threadIdx.x - o] : 0;
        __syncthreads();
        sums[threadIdx.x] += t;
        __syncthreads();
    }
    int excl = sums[threadIdx.x] - s;
#pragma unroll
    for (int j = 0; j < W; ++j) { row[threadIdx.x * W + j] = excl; excl += v[j]; }
    if (threadIdx.x == 255) bintot[blockIdx.x] = sums[255];
}

// ---- S2: exclusive scan of bin totals -> binbase
__global__ void s2_scan(const int* __restrict__ bintot, int* __restrict__ binbase,
                        int nbins, int ne) {
    __shared__ int tmp[1024];
    int tid = threadIdx.x;
    int v = (tid < nbins) ? bintot[tid] : 0;
    tmp[tid] = v;
    __syncthreads();
    for (int o = 1; o < 1024; o <<= 1) {
        int t = (tid >= o) ? tmp[tid - o] : 0;
        __syncthreads();
        tmp[tid] += t;
        __syncthreads();
    }
    if (tid < nbins) binbase[tid] = tmp[tid] - v;
    if (tid == 0) binbase[nbins] = ne;
}

// ---- P1b: LDS tile-sort + coalesced flush into bin-grouped u64 array
__global__ void p1b_scatter(const int* __restrict__ src, const int* __restrict__ dst,
                            const float* __restrict__ ew, const int* __restrict__ bh,
                            const int* __restrict__ binbase,
                            unsigned long long* __restrict__ b64,
                            int ne, int nbins, int chunk) {
    __shared__ unsigned long long stage[TILE];
    __shared__ int hist[MAXBINS];
    __shared__ int boff[MAXBINS];
    __shared__ int cur[MAXBINS];
    __shared__ int ssum[256];
    constexpr int MPT = TILE / 256;
    for (int k = threadIdx.x; k < nbins; k += 256)
        cur[k] = binbase[k] + bh[(size_t)k * NB1 + blockIdx.x];
    int base = blockIdx.x * chunk;
    int endb = min(base + chunk, ne);
    for (int t0 = base; t0 < endb; t0 += TILE) {
        int cnt = min(TILE, endb - t0);
        for (int k = threadIdx.x; k < nbins; k += 256) hist[k] = 0;
        __syncthreads();
        unsigned long long ent[MPT];
        int m = 0;
        for (int j = threadIdx.x; j < cnt; j += 256) {
            int e = t0 + j;
            int d = dst[e];
            float w = sigmoidf_(ew[e]);
            int q = (int)fminf(w * QS + 0.5f, 16383.0f);
            int b = d >> 8;
            ent[m++] = (unsigned long long)((unsigned)src[e] | ((unsigned)q << 18))
                     | ((unsigned long long)(d & 255) << 32)
                     | ((unsigned long long)b << 40);
            atomicAdd(&hist[b], 1);
        }
        __syncthreads();
        int w0 = threadIdx.x * 4;
        int lv[4];
        int ls = 0;
#pragma unroll
        for (int j = 0; j < 4; ++j) {
            int idx = w0 + j;
            lv[j] = (idx < nbins) ? hist[idx] : 0;
            ls += lv[j];
        }
        ssum[threadIdx.x] = ls;
        __syncthreads();
        for (int o = 1; o < 256; o <<= 1) {
            int t = (threadIdx.x >= o) ? ssum[threadIdx.x - o] : 0;
            __syncthreads();
            ssum[threadIdx.x] += t;
            __syncthreads();
        }
        int excl = ssum[threadIdx.x] - ls;
#pragma unroll
        for (int j = 0; j < 4; ++j) {
            int idx = w0 + j;
            if (idx < nbins) { boff[idx] = excl; excl += lv[j]; }
        }
        __syncthreads();
        for (int k = threadIdx.x; k < nbins; k += 256) hist[k] = 0;
        __syncthreads();
        for (int j = 0; j < m; ++j) {
            int b = (int)(ent[j] >> 40);
            int p = boff[b] + atomicAdd(&hist[b], 1);
            stage[p] = ent[j];
        }
        __syncthreads();
        for (int j = threadIdx.x; j < cnt; j += 256) {
            unsigned long long v = stage[j];
            int b = (int)(v >> 40);
            b64[cur[b] + (j - boff[b])] = v;
        }
        __syncthreads();
        for (int k = threadIdx.x; k < nbins; k += 256) cur[k] += hist[k];
        __syncthreads();
    }
}

// ---- P2: per-bin CSR finalize + dinv + fused g0 = dinv (.) (x @ W1) fp16
__global__ void p2_build(const unsigned long long* __restrict__ b64,
                         const int* __restrict__ binbase, unsigned* __restrict__ edata,
                         int* __restrict__ C, float* __restrict__ dinv,
                         const float* __restrict__ x, const float* __restrict__ W1,
                         _Float16* __restrict__ g0, int n, int ne, int nbins) {
    __shared__ int cnt[NPB];
    __shared__ int rs[NPB];
    __shared__ int curs[NPB];
    __shared__ unsigned qsum[NPB];
    __shared__ float Ws[56];
    if (threadIdx.x < 56) Ws[threadIdx.x] = W1[threadIdx.x];
    int b = blockIdx.x;
    int E0 = binbase[b], E1 = binbase[b + 1];
    cnt[threadIdx.x] = 0;
    qsum[threadIdx.x] = 0;
    __syncthreads();
    for (int k = E0 + threadIdx.x; k < E1; k += 256)
        atomicAdd(&cnt[(int)((b64[k] >> 32) & 0xFF)], 1);
    __syncthreads();
    int v = cnt[threadIdx.x];
    rs[threadIdx.x] = v;
    __syncthreads();
    for (int o = 1; o < NPB; o <<= 1) {
        int t = (threadIdx.x >= o) ? rs[threadIdx.x - o] : 0;
        __syncthreads();
        rs[threadIdx.x] += t;
        __syncthreads();
    }
    int excl = rs[threadIdx.x] - v;
    curs[threadIdx.x] = E0 + excl;
    int node = b * NPB + threadIdx.x;
    if (node < n) C[node] = E0 + excl;
    if (b == 0 && threadIdx.x == 0) C[n] = ne;
    __syncthreads();
    for (int k = E0 + threadIdx.x; k < E1; k += 256) {
        unsigned long long e64 = b64[k];
        int dl = (int)((e64 >> 32) & 0xFF);
        int pos = atomicAdd(&curs[dl], 1);
        edata[pos] = (unsigned)(e64 & 0xFFFFFFFFu);
        atomicAdd(&qsum[dl], (unsigned)((e64 >> 18) & 0x3FFFu));
    }
    __syncthreads();
    if (node < n) {
        float dv = rsqrtf((float)qsum[threadIdx.x] * QINV + 1.0f);
        dinv[node] = dv;
        float xi[7];
#pragma unroll
        for (int k = 0; k < 7; ++k) xi[k] = x[(size_t)node * 7 + k];
        h8 r;
#pragma unroll
        for (int o = 0; o < 8; ++o) {
            float acc = 0.0f;
#pragma unroll
            for (int k = 0; k < 7; ++k) acc = fmaf(xi[k], Ws[k * 8 + o], acc);
            r[o] = (_Float16)(acc * dv);
        }
        *reinterpret_cast<h8*>(g0 + (size_t)node * 8) = r;
    }
}

// ---- gather1 (8 lanes/node: 4 feat-pairs x 2 edge-halves)
__global__ void gather1_kernel(const _Float16* __restrict__ g, const float* __restrict__ dinv,
                               const int* __restrict__ C, const unsigned* __restrict__ edata,
                               const float* __restrict__ b1, _Float16* __restrict__ out, int n) {
    __shared__ float bs[8];
    if (threadIdx.x < 8) bs[threadIdx.x] = b1[threadIdx.x];
    __syncthreads();
    long long t = (long long)blockIdx.x * blockDim.x + threadIdx.x;
    int i = (int)(t >> 3);
    int sub = (int)(t & 3);
    int half = (int)((t >> 2) & 1);
    if (i >= n) return;
    int beg = C[i], end = C[i + 1];
    float a0 = 0.0f, a1 = 0.0f;
    if (half == 0) {
        h2 r0 = *reinterpret_cast<const h2*>(g + (size_t)i * 8 + sub * 2);
        a0 = (float)r0[0]; a1 = (float)r0[1];
    }
    for (int k = beg + half; k < end; k += 2) {
        unsigned v = edata[k];
        int s = (int)(v & 0x3FFFFu);
        float w = (float)(v >> 18) * QINV;
        h2 r = *reinterpret_cast<const h2*>(g + (size_t)s * 8 + sub * 2);
        a0 = fmaf((float)r[0], w, a0);
        a1 = fmaf((float)r[1], w, a1);
    }
    // merge edge halves (lanes differ in bit 2)
    a0 += __shfl_xor(a0, 4, 64);
    a1 += __shfl_xor(a1, 4, 64);
    if (half == 0) {
        float dv = dinv[i];
        h2 o2;
        o2[0] = (_Float16)(dv * fmaxf(dv * a0 + bs[sub * 2 + 0], 0.0f));
        o2[1] = (_Float16)(dv * fmaxf(dv * a1 + bs[sub * 2 + 1], 0.0f));
        *reinterpret_cast<h2*>(out + (size_t)i * 8 + sub * 2) = o2;
    }
}

// ---- gather2 (8 lanes/node) + fused dense 8->16
__global__ void gather2_kernel(const _Float16* __restrict__ g, const float* __restrict__ dinv,
                               const int* __restrict__ C, const unsigned* __restrict__ edata,
                               const float* __restrict__ W2, const float* __restrict__ b2,
                               _Float16* __restrict__ out, int n) {
    __shared__ float Ws[128];
    __shared__ float bs[16];
    if (threadIdx.x < 128) Ws[threadIdx.x] = W2[threadIdx.x];
    if (threadIdx.x < 16) bs[threadIdx.x] = b2[threadIdx.x];
    __syncthreads();
    long long t = (long long)blockIdx.x * blockDim.x + threadIdx.x;
    int i = (int)(t >> 3);
    int sub = (int)(t & 3);
    int half = (int)((t >> 2) & 1);
    if (i >= n) return;
    int beg = C[i], end = C[i + 1];
    float acc[2] = {0.0f, 0.0f};
    if (half == 0) {
        h2 r0 = *reinterpret_cast<const h2*>(g + (size_t)i * 8 + sub * 2);
        acc[0] = (float)r0[0]; acc[1] = (float)r0[1];
    }
    for (int k = beg + half; k < end; k += 2) {
        unsigned v = edata[k];
        int s = (int)(v & 0x3FFFFu);
        float w = (float)(v >> 18) * QINV;
        h2 r = *reinterpret_cast<const h2*>(g + (size_t)s * 8 + sub * 2);
        acc[0] = fmaf((float)r[0], w, acc[0]);
        acc[1] = fmaf((float)r[1], w, acc[1]);
    }
    acc[0] += __shfl_xor(acc[0], 4, 64);
    acc[1] += __shfl_xor(acc[1], 4, 64);
    float dv = dinv[i];
    acc[0] *= dv; acc[1] *= dv;  // raw2 slice (both halves now identical)
    // rebuild full raw2[8] across the feature quad (lanes xor 1,2)
    float pv[4], raw[8];
    int oo = (sub & 1) * 2;
#pragma unroll
    for (int j = 0; j < 2; ++j) {
        float o1 = __shfl_xor(acc[j], 1, 64);
        pv[oo + j] = acc[j];
        pv[(oo ^ 2) + j] = o1;
    }
    int pb = (sub & 2) * 2;
#pragma unroll
    for (int j = 0; j < 4; ++j) {
        float o2v = __shfl_xor(pv[j], 2, 64);
        raw[pb + j] = pv[j];
        raw[(pb ^ 4) + j] = o2v;
    }
    if (half == 0) {
        h4 o4;
#pragma unroll
        for (int jo = 0; jo < 4; ++jo) {
            int o = sub * 4 + jo;
            float h = bs[o];
#pragma unroll
            for (int k = 0; k < 8; ++k) h = fmaf(raw[k], Ws[k * 16 + o], h);
            o4[jo] = (_Float16)(dv * fmaxf(h, 0.0f));
        }
        *reinterpret_cast<h4*>(out + (size_t)i * 16 + sub * 4) = o4;
    }
}

// ---- gather3 (8 lanes/node) + fused dense 16->32 + head proj -> pq fp16
__global__ void gather3_kernel(const _Float16* __restrict__ g, const float* __restrict__ dinv,
                               const int* __restrict__ C, const unsigned* __restrict__ edata,
                               const float* __restrict__ W3, const float* __restrict__ b3,
                               const float* __restrict__ Wl1, const float* __restrict__ bl1,
                               const float* __restrict__ Wl2, const float* __restrict__ bl2,
                               _Float16* __restrict__ pqh, int n) {
    __shared__ float Ws[512];
    __shared__ float bs[32];
    __shared__ float wfs[192];
    __shared__ float bfs[3];
    for (int k = threadIdx.x; k < 512; k += 256) Ws[k] = W3[k];
    if (threadIdx.x < 32) bs[threadIdx.x] = b3[threadIdx.x];
    if (threadIdx.x < 192) {
        int f = threadIdx.x / 3, j = threadIdx.x % 3;
        float acc = 0.0f;
#pragma unroll
        for (int k = 0; k < 4; ++k) acc = fmaf(Wl1[f * 4 + k], Wl2[k * 3 + j], acc);
        wfs[threadIdx.x] = acc;
    }
    if (threadIdx.x < 3) {
        float acc = bl2[threadIdx.x];
#pragma unroll
        for (int k = 0; k < 4; ++k) acc = fmaf(bl1[k], Wl2[k * 3 + threadIdx.x], acc);
        bfs[threadIdx.x] = acc;
    }
    __syncthreads();
    long long t = (long long)blockIdx.x * blockDim.x + threadIdx.x;
    int i = (int)(t >> 3);
    int sub = (int)(t & 3);
    int half = (int)((t >> 2) & 1);
    if (i >= n) return;
    int beg = C[i], end = C[i + 1];
    float acc[4] = {0.0f, 0.0f, 0.0f, 0.0f};
    if (half == 0) {
        h4 r0 = *reinterpret_cast<const h4*>(g + (size_t)i * 16 + sub * 4);
#pragma unroll
        for (int j = 0; j < 4; ++j) acc[j] = (float)r0[j];
    }
    for (int k = beg + half; k < end; k += 2) {
        unsigned v = edata[k];
        int s = (int)(v & 0x3FFFFu);
        float w = (float)(v >> 18) * QINV;
        h4 r = *reinterpret_cast<const h4*>(g + (size_t)s * 16 + sub * 4);
#pragma unroll
        for (int j = 0; j < 4; ++j) acc[j] = fmaf((float)r[j], w, acc[j]);
    }
#pragma unroll
    for (int j = 0; j < 4; ++j) acc[j] += __shfl_xor(acc[j], 4, 64);
    float dv = dinv[i];
#pragma unroll
    for (int j = 0; j < 4; ++j) acc[j] *= dv;  // raw3 slice (halves identical)
    // rebuild full raw3[16] across the feature quad
    float pv[8], raw[16];
    int oo = (sub & 1) * 4;
#pragma unroll
    for (int j = 0; j < 4; ++j) {
        float o1 = __shfl_xor(acc[j], 1, 64);
        pv[oo + j] = acc[j];
        pv[(oo ^ 4) + j] = o1;
    }
    int pb = (sub & 2) * 4;
#pragma unroll
    for (int j = 0; j < 8; ++j) {
        float o2v = __shfl_xor(pv[j], 2, 64);
        raw[pb + j] = pv[j];
        raw[(pb ^ 8) + j] = o2v;
    }
    // dense 16->32 + head projection; lane handles o = sub*8 .. sub*8+7
    float p0 = (sub == 0) ? bfs[0] : 0.0f;
    float p1 = (sub == 0) ? bfs[1] : 0.0f;
    float p2 = (sub == 0) ? bfs[2] : 0.0f;
    float q0 = 0.0f, q1 = 0.0f, q2 = 0.0f;
#pragma unroll
    for (int jo = 0; jo < 8; ++jo) {
        int o = sub * 8 + jo;
        float h = bs[o];
#pragma unroll
        for (int k = 0; k < 16; ++k) h = fmaf(raw[k], Ws[k * 32 + o], h);
        h = fmaxf(h, 0.0f);
        p0 = fmaf(h, wfs[o * 3 + 0], p0);
        p1 = fmaf(h, wfs[o * 3 + 1], p1);
        p2 = fmaf(h, wfs[o * 3 + 2], p2);
        q0 = fmaf(h, wfs[(32 + o) * 3 + 0], q0);
        q1 = fmaf(h, wfs[(32 + o) * 3 + 1], q1);
        q2 = fmaf(h, wfs[(32 + o) * 3 + 2], q2);
    }
    // reduce across feature quad (both halves hold identical results)
    p0 += __shfl_xor(p0, 1, 64); p0 += __shfl_xor(p0, 2, 64);
    p1 += __shfl_xor(p1, 1, 64); p1 += __shfl_xor(p1, 2, 64);
    p2 += __shfl_xor(p2, 1, 64); p2 += __shfl_xor(p2, 2, 64);
    q0 += __shfl_xor(q0, 1, 64); q0 += __shfl_xor(q0, 2, 64);
    q1 += __shfl_xor(q1, 1, 64); q1 += __shfl_xor(q1, 2, 64);
    q2 += __shfl_xor(q2, 1, 64); q2 += __shfl_xor(q2, 2, 64);
    if (sub == 0 && half == 0) {
        h8 o8;
        o8[0] = (_Float16)p0; o8[1] = (_Float16)p1; o8[2] = (_Float16)p2; o8[3] = (_Float16)0.0f;
        o8[4] = (_Float16)q0; o8[5] = (_Float16)q1; o8[6] = (_Float16)q2; o8[7] = (_Float16)0.0f;
        *reinterpret_cast<h8*>(pqh + (size_t)i * 8) = o8;
    }
}

// ---- head: out[e] = p[a] + q[b]   (fp16 pq table, fp32 out)
__global__ void head_kernel(const int* __restrict__ w2b, const _Float16* __restrict__ pqh,
                            float* __restrict__ out, int nw) {
    int e = blockIdx.x * blockDim.x + threadIdx.x;
    if (e >= nw) return;
    int a = w2b[e];
    int b = w2b[(size_t)nw + e];
    h4 P = *reinterpret_cast<const h4*>(pqh + (size_t)a * 8);
    h4 Q = *reinterpret_cast<const h4*>(pqh + (size_t)b * 8 + 4);
    out[(size_t)e * 3 + 0] = (float)P[0] + (float)Q[0];
    out[(size_t)e * 3 + 1] = (float)P[1] + (float)Q[1];
    out[(size_t)e * 3 + 2] = (float)P[2] + (float)Q[2];
}

extern "C" void kernel_launch(void* const* d_in, const int* in_sizes, int n_in,
                              void* d_out, int out_size, void* d_ws, size_t ws_size,
                              hipStream_t stream) {
    const float* x   = (const float*)d_in[0];
    const int* eidx  = (const int*)d_in[1];
    const int* w2b   = (const int*)d_in[2];
    const float* ew  = (const float*)d_in[3];
    const float* W1  = (const float*)d_in[4];
    const float* b1  = (const float*)d_in[5];
    const float* W2  = (const float*)d_in[6];
    const float* b2  = (const float*)d_in[7];
    const float* W3  = (const float*)d_in[8];
    const float* b3  = (const float*)d_in[9];
    const float* Wl1 = (const float*)d_in[10];
    const float* bl1 = (const float*)d_in[11];
    const float* Wl2 = (const float*)d_in[12];
    const float* bl2 = (const float*)d_in[13];
    float* out = (float*)d_out;

    const int n  = in_sizes[0] / 7;   // 200000
    const int ne = in_sizes[1] / 2;   // 4000000
    const int nw = in_sizes[2] / 2;   // 2000000
    const int* src = eidx;
    const int* dst = eidx + ne;

    const int nbins = (n + NPB - 1) / NPB;    // 782
    const int chunk = (ne + NB1 - 1) / NB1;   // 5209

    // ---- workspace layout (4B words) ----
    float*     ws      = (float*)d_ws;
    float*     dinv    = ws;                                    // n
    int*       C       = (int*)(ws + n);                        // n+1 (+pad)
    unsigned*  edata   = (unsigned*)(ws + 2 * (size_t)n + 16);  // ne
    int*       bh      = (int*)(edata + ne);                    // nbins*NB1
    int*       bintot  = bh + (size_t)nbins * NB1;              // MAXBINS
    int*       binbase = bintot + MAXBINS;                      // MAXBINS
    _Float16*  g0      = (_Float16*)(binbase + MAXBINS);        // 8n halves (2n words)
    float*     bregion = (float*)(g0 + (size_t)n * 8);          // 2*ne words
    unsigned long long* b64 = (unsigned long long*)bregion;     // ne u64 (dead after p2)
    _Float16*  g1      = (_Float16*)bregion;                    // 8n halves  } alias
    _Float16*  g2      = (_Float16*)(bregion + 4 * (size_t)n);  // 16n halves } into
    _Float16*  pqh     = (_Float16*)(bregion + 12 * (size_t)n); // 8n halves  } b64

    const int Bl = 256;
    auto blks = [&](long long t) { return (int)((t + Bl - 1) / Bl); };
    const int nb8 = blks((long long)n * 8);  // 8 lanes per node

    // 1. CSR build (counting sort; tile-sorted write-combined scatter)
    p1a_hist<<<NB1, Bl, 0, stream>>>(dst, bh, ne, nbins, chunk);
    s1_scan<<<nbins, Bl, 0, stream>>>(bh, bintot);
    s2_scan<<<1, 1024, 0, stream>>>(bintot, binbase, nbins, ne);
    p1b_scatter<<<NB1, Bl, 0, stream>>>(src, dst, ew, bh, binbase, b64, ne, nbins, chunk);
    p2_build<<<nbins, Bl, 0, stream>>>(b64, binbase, edata, C, dinv, x, W1, g0, n, ne, nbins);

    // 2. three fused 8-lane-per-node gather layers
    gather1_kernel<<<nb8, Bl, 0, stream>>>(g0, dinv, C, edata, b1, g1, n);
    gather2_kernel<<<nb8, Bl, 0, stream>>>(g1, dinv, C, edata, W2, b2, g2, n);
    gather3_kernel<<<nb8, Bl, 0, stream>>>(g2, dinv, C, edata, W3, b3,
                                           Wl1, bl1, Wl2, bl2, pqh, n);

    // 3. head
    head_kernel<<<blks(nw), Bl, 0, stream>>>(w2b, pqh, out, nw);
}

// Round 12
// 397.018 us; speedup vs baseline: 2.6986x; 1.0053x over previous
//
#include <hip/hip_runtime.h>
#include <hip/hip_bf16.h>
#include <hip/hip_fp16.h>

// GCN 3-layer + edge-MLP head. R12 = R11 + de-duplicated fused-dense epilogues:
// the 8 lanes of a node group (4 feat-split x 2 edge-half) now SPLIT the dense
// output range 8 ways after the half-merge (R11 computed each output twice).
// R10 lesson: LDS-atomic bin gather is 2.6x worse than register accumulation.
//
// Build: bin = dst>>8. p1a per-(bin,block) LDS histogram; s1/s2 scans; p1b LDS
// tile-sort + write-combined flush of u64(src|q<<18|dl<<32|bin<<40); p2 per-bin
// CSR finalize (node-sorted 4B edata + C + dinv + fused g0 = dinv(.)(x@W1) fp16).
// gathers: g=dinv(.)h fp16 tables, fp32 accum; denses fused into epilogues.
// head: out[e] = p[a] + q[b] from fp16 pq table.

#define NB1 768
#define NPB 256
#define MAXBINS 1024
#define TILE 4096
#define QS 16384.0f
#define QINV (1.0f / 16384.0f)

typedef _Float16 h2 __attribute__((ext_vector_type(2)));
typedef _Float16 h4 __attribute__((ext_vector_type(4)));
typedef _Float16 h8 __attribute__((ext_vector_type(8)));

__device__ __forceinline__ float sigmoidf_(float x) {
    return 1.0f / (1.0f + __expf(-x));
}

// ---- P1a: per-(bin,block) histogram via LDS
__global__ void p1a_hist(const int* __restrict__ dst, int* __restrict__ bh,
                         int ne, int nbins, int chunk) {
    __shared__ int h[MAXBINS];
    for (int k = threadIdx.x; k < nbins; k += 256) h[k] = 0;
    __syncthreads();
    int base = blockIdx.x * chunk;
    int end = min(base + chunk, ne);
    for (int e = base + threadIdx.x; e < end; e += 256)
        atomicAdd(&h[dst[e] >> 8], 1);
    __syncthreads();
    for (int k = threadIdx.x; k < nbins; k += 256)
        bh[(size_t)k * NB1 + blockIdx.x] = h[k];
}

// ---- S1: per-bin exclusive scan over NB1 block counts + bin totals
__global__ void s1_scan(int* __restrict__ bh, int* __restrict__ bintot) {
    __shared__ int sums[256];
    constexpr int W = NB1 / 256;
    int* row = bh + (size_t)blockIdx.x * NB1;
    int v[W];
    int s = 0;
#pragma unroll
    for (int j = 0; j < W; ++j) { v[j] = row[threadIdx.x * W + j]; s += v[j]; }
    sums[threadIdx.x] = s;
    __syncthreads();
    for (int o = 1; o < 256; o <<= 1) {
        int t = (threadIdx.x >= o) ? sums[threadIdx.x - o] : 0;
        __syncthreads();
        sums[threadIdx.x] += t;
        __syncthreads();
    }
    int excl = sums[threadIdx.x] - s;
#pragma unroll
    for (int j = 0; j < W; ++j) { row[threadIdx.x * W + j] = excl; excl += v[j]; }
    if (threadIdx.x == 255) bintot[blockIdx.x] = sums[255];
}

// ---- S2: exclusive scan of bin totals -> binbase
__global__ void s2_scan(const int* __restrict__ bintot, int* __restrict__ binbase,
                        int nbins, int ne) {
    __shared__ int tmp[1024];
    int tid = threadIdx.x;
    int v = (tid < nbins) ? bintot[tid] : 0;
    tmp[tid] = v;
    __syncthreads();
    for (int o = 1; o < 1024; o <<= 1) {
        int t = (tid >= o) ? tmp[tid - o] : 0;
        __syncthreads();
        tmp[tid] += t;
        __syncthreads();
    }
    if (tid < nbins) binbase[tid] = tmp[tid] - v;
    if (tid == 0) binbase[nbins] = ne;
}

// ---- P1b: LDS tile-sort + coalesced flush into bin-grouped u64 array
__global__ void p1b_scatter(const int* __restrict__ src, const int* __restrict__ dst,
                            const float* __restrict__ ew, const int* __restrict__ bh,
                            const int* __restrict__ binbase,
                            unsigned long long* __restrict__ b64,
                            int ne, int nbins, int chunk) {
    __shared__ unsigned long long stage[TILE];
    __shared__ int hist[MAXBINS];
    __shared__ int boff[MAXBINS];
    __shared__ int cur[MAXBINS];
    __shared__ int ssum[256];
    constexpr int MPT = TILE / 256;
    for (int k = threadIdx.x; k < nbins; k += 256)
        cur[k] = binbase[k] + bh[(size_t)k * NB1 + blockIdx.x];
    int base = blockIdx.x * chunk;
    int endb = min(base + chunk, ne);
    for (int t0 = base; t0 < endb; t0 += TILE) {
        int cnt = min(TILE, endb - t0);
        for (int k = threadIdx.x; k < nbins; k += 256) hist[k] = 0;
        __syncthreads();
        unsigned long long ent[MPT];
        int m = 0;
        for (int j = threadIdx.x; j < cnt; j += 256) {
            int e = t0 + j;
            int d = dst[e];
            float w = sigmoidf_(ew[e]);
            int q = (int)fminf(w * QS + 0.5f, 16383.0f);
            int b = d >> 8;
            ent[m++] = (unsigned long long)((unsigned)src[e] | ((unsigned)q << 18))
                     | ((unsigned long long)(d & 255) << 32)
                     | ((unsigned long long)b << 40);
            atomicAdd(&hist[b], 1);
        }
        __syncthreads();
        int w0 = threadIdx.x * 4;
        int lv[4];
        int ls = 0;
#pragma unroll
        for (int j = 0; j < 4; ++j) {
            int idx = w0 + j;
            lv[j] = (idx < nbins) ? hist[idx] : 0;
            ls += lv[j];
        }
        ssum[threadIdx.x] = ls;
        __syncthreads();
        for (int o = 1; o < 256; o <<= 1) {
            int t = (threadIdx.x >= o) ? ssum[threadIdx.x - o] : 0;
            __syncthreads();
            ssum[threadIdx.x] += t;
            __syncthreads();
        }
        int excl = ssum[threadIdx.x] - ls;
#pragma unroll
        for (int j = 0; j < 4; ++j) {
            int idx = w0 + j;
            if (idx < nbins) { boff[idx] = excl; excl += lv[j]; }
        }
        __syncthreads();
        for (int k = threadIdx.x; k < nbins; k += 256) hist[k] = 0;
        __syncthreads();
        for (int j = 0; j < m; ++j) {
            int b = (int)(ent[j] >> 40);
            int p = boff[b] + atomicAdd(&hist[b], 1);
            stage[p] = ent[j];
        }
        __syncthreads();
        for (int j = threadIdx.x; j < cnt; j += 256) {
            unsigned long long v = stage[j];
            int b = (int)(v >> 40);
            b64[cur[b] + (j - boff[b])] = v;
        }
        __syncthreads();
        for (int k = threadIdx.x; k < nbins; k += 256) cur[k] += hist[k];
        __syncthreads();
    }
}

// ---- P2: per-bin CSR finalize + dinv + fused g0 = dinv (.) (x @ W1) fp16
__global__ void p2_build(const unsigned long long* __restrict__ b64,
                         const int* __restrict__ binbase, unsigned* __restrict__ edata,
                         int* __restrict__ C, float* __restrict__ dinv,
                         const float* __restrict__ x, const float* __restrict__ W1,
                         _Float16* __restrict__ g0, int n, int ne, int nbins) {
    __shared__ int cnt[NPB];
    __shared__ int rs[NPB];
    __shared__ int curs[NPB];
    __shared__ unsigned qsum[NPB];
    __shared__ float Ws[56];
    if (threadIdx.x < 56) Ws[threadIdx.x] = W1[threadIdx.x];
    int b = blockIdx.x;
    int E0 = binbase[b], E1 = binbase[b + 1];
    cnt[threadIdx.x] = 0;
    qsum[threadIdx.x] = 0;
    __syncthreads();
    for (int k = E0 + threadIdx.x; k < E1; k += 256)
        atomicAdd(&cnt[(int)((b64[k] >> 32) & 0xFF)], 1);
    __syncthreads();
    int v = cnt[threadIdx.x];
    rs[threadIdx.x] = v;
    __syncthreads();
    for (int o = 1; o < NPB; o <<= 1) {
        int t = (threadIdx.x >= o) ? rs[threadIdx.x - o] : 0;
        __syncthreads();
        rs[threadIdx.x] += t;
        __syncthreads();
    }
    int excl = rs[threadIdx.x] - v;
    curs[threadIdx.x] = E0 + excl;
    int node = b * NPB + threadIdx.x;
    if (node < n) C[node] = E0 + excl;
    if (b == 0 && threadIdx.x == 0) C[n] = ne;
    __syncthreads();
    for (int k = E0 + threadIdx.x; k < E1; k += 256) {
        unsigned long long e64 = b64[k];
        int dl = (int)((e64 >> 32) & 0xFF);
        int pos = atomicAdd(&curs[dl], 1);
        edata[pos] = (unsigned)(e64 & 0xFFFFFFFFu);
        atomicAdd(&qsum[dl], (unsigned)((e64 >> 18) & 0x3FFFu));
    }
    __syncthreads();
    if (node < n) {
        float dv = rsqrtf((float)qsum[threadIdx.x] * QINV + 1.0f);
        dinv[node] = dv;
        float xi[7];
#pragma unroll
        for (int k = 0; k < 7; ++k) xi[k] = x[(size_t)node * 7 + k];
        h8 r;
#pragma unroll
        for (int o = 0; o < 8; ++o) {
            float acc = 0.0f;
#pragma unroll
            for (int k = 0; k < 7; ++k) acc = fmaf(xi[k], Ws[k * 8 + o], acc);
            r[o] = (_Float16)(acc * dv);
        }
        *reinterpret_cast<h8*>(g0 + (size_t)node * 8) = r;
    }
}

// ---- gather1 (8 lanes/node: 4 feat-pairs x 2 edge-halves)
__global__ void gather1_kernel(const _Float16* __restrict__ g, const float* __restrict__ dinv,
                               const int* __restrict__ C, const unsigned* __restrict__ edata,
                               const float* __restrict__ b1, _Float16* __restrict__ out, int n) {
    __shared__ float bs[8];
    if (threadIdx.x < 8) bs[threadIdx.x] = b1[threadIdx.x];
    __syncthreads();
    long long t = (long long)blockIdx.x * blockDim.x + threadIdx.x;
    int i = (int)(t >> 3);
    int sub = (int)(t & 3);
    int half = (int)((t >> 2) & 1);
    if (i >= n) return;
    int beg = C[i], end = C[i + 1];
    float a0 = 0.0f, a1 = 0.0f;
    if (half == 0) {
        h2 r0 = *reinterpret_cast<const h2*>(g + (size_t)i * 8 + sub * 2);
        a0 = (float)r0[0]; a1 = (float)r0[1];
    }
    for (int k = beg + half; k < end; k += 2) {
        unsigned v = edata[k];
        int s = (int)(v & 0x3FFFFu);
        float w = (float)(v >> 18) * QINV;
        h2 r = *reinterpret_cast<const h2*>(g + (size_t)s * 8 + sub * 2);
        a0 = fmaf((float)r[0], w, a0);
        a1 = fmaf((float)r[1], w, a1);
    }
    // merge edge halves (lanes differ in bit 2)
    a0 += __shfl_xor(a0, 4, 64);
    a1 += __shfl_xor(a1, 4, 64);
    if (half == 0) {
        float dv = dinv[i];
        h2 o2;
        o2[0] = (_Float16)(dv * fmaxf(dv * a0 + bs[sub * 2 + 0], 0.0f));
        o2[1] = (_Float16)(dv * fmaxf(dv * a1 + bs[sub * 2 + 1], 0.0f));
        *reinterpret_cast<h2*>(out + (size_t)i * 8 + sub * 2) = o2;
    }
}

// ---- gather2 (8 lanes/node) + fused dense 8->16, outputs split 8 ways
__global__ void gather2_kernel(const _Float16* __restrict__ g, const float* __restrict__ dinv,
                               const int* __restrict__ C, const unsigned* __restrict__ edata,
                               const float* __restrict__ W2, const float* __restrict__ b2,
                               _Float16* __restrict__ out, int n) {
    __shared__ float Ws[128];
    __shared__ float bs[16];
    if (threadIdx.x < 128) Ws[threadIdx.x] = W2[threadIdx.x];
    if (threadIdx.x < 16) bs[threadIdx.x] = b2[threadIdx.x];
    __syncthreads();
    long long t = (long long)blockIdx.x * blockDim.x + threadIdx.x;
    int i = (int)(t >> 3);
    int sub = (int)(t & 3);
    int half = (int)((t >> 2) & 1);
    if (i >= n) return;
    int beg = C[i], end = C[i + 1];
    float acc[2] = {0.0f, 0.0f};
    if (half == 0) {
        h2 r0 = *reinterpret_cast<const h2*>(g + (size_t)i * 8 + sub * 2);
        acc[0] = (float)r0[0]; acc[1] = (float)r0[1];
    }
    for (int k = beg + half; k < end; k += 2) {
        unsigned v = edata[k];
        int s = (int)(v & 0x3FFFFu);
        float w = (float)(v >> 18) * QINV;
        h2 r = *reinterpret_cast<const h2*>(g + (size_t)s * 8 + sub * 2);
        acc[0] = fmaf((float)r[0], w, acc[0]);
        acc[1] = fmaf((float)r[1], w, acc[1]);
    }
    acc[0] += __shfl_xor(acc[0], 4, 64);
    acc[1] += __shfl_xor(acc[1], 4, 64);
    float dv = dinv[i];
    acc[0] *= dv; acc[1] *= dv;  // raw2 slice (both halves now identical)
    // rebuild full raw2[8] across the feature quad (lanes xor 1,2)
    float pv[4], raw[8];
    int oo = (sub & 1) * 2;
#pragma unroll
    for (int j = 0; j < 2; ++j) {
        float o1 = __shfl_xor(acc[j], 1, 64);
        pv[oo + j] = acc[j];
        pv[(oo ^ 2) + j] = o1;
    }
    int pb = (sub & 2) * 2;
#pragma unroll
    for (int j = 0; j < 4; ++j) {
        float o2v = __shfl_xor(pv[j], 2, 64);
        raw[pb + j] = pv[j];
        raw[(pb ^ 4) + j] = o2v;
    }
    // dense: lane (half*4+sub) computes outputs o = lane8*2 .. +1 (2 of 16)
    int lane8 = half * 4 + sub;
    h2 o2;
#pragma unroll
    for (int jo = 0; jo < 2; ++jo) {
        int o = lane8 * 2 + jo;
        float h = bs[o];
#pragma unroll
        for (int k = 0; k < 8; ++k) h = fmaf(raw[k], Ws[k * 16 + o], h);
        o2[jo] = (_Float16)(dv * fmaxf(h, 0.0f));
    }
    *reinterpret_cast<h2*>(out + (size_t)i * 16 + lane8 * 2) = o2;
}

// ---- gather3 (8 lanes/node) + fused dense 16->32 + head proj, outputs split 8 ways
__global__ void gather3_kernel(const _Float16* __restrict__ g, const float* __restrict__ dinv,
                               const int* __restrict__ C, const unsigned* __restrict__ edata,
                               const float* __restrict__ W3, const float* __restrict__ b3,
                               const float* __restrict__ Wl1, const float* __restrict__ bl1,
                               const float* __restrict__ Wl2, const float* __restrict__ bl2,
                               _Float16* __restrict__ pqh, int n) {
    __shared__ float Ws[512];
    __shared__ float bs[32];
    __shared__ float wfs[192];
    __shared__ float bfs[3];
    for (int k = threadIdx.x; k < 512; k += 256) Ws[k] = W3[k];
    if (threadIdx.x < 32) bs[threadIdx.x] = b3[threadIdx.x];
    if (threadIdx.x < 192) {
        int f = threadIdx.x / 3, j = threadIdx.x % 3;
        float acc = 0.0f;
#pragma unroll
        for (int k = 0; k < 4; ++k) acc = fmaf(Wl1[f * 4 + k], Wl2[k * 3 + j], acc);
        wfs[threadIdx.x] = acc;
    }
    if (threadIdx.x < 3) {
        float acc = bl2[threadIdx.x];
#pragma unroll
        for (int k = 0; k < 4; ++k) acc = fmaf(bl1[k], Wl2[k * 3 + threadIdx.x], acc);
        bfs[threadIdx.x] = acc;
    }
    __syncthreads();
    long long t = (long long)blockIdx.x * blockDim.x + threadIdx.x;
    int i = (int)(t >> 3);
    int sub = (int)(t & 3);
    int half = (int)((t >> 2) & 1);
    if (i >= n) return;
    int beg = C[i], end = C[i + 1];
    float acc[4] = {0.0f, 0.0f, 0.0f, 0.0f};
    if (half == 0) {
        h4 r0 = *reinterpret_cast<const h4*>(g + (size_t)i * 16 + sub * 4);
#pragma unroll
        for (int j = 0; j < 4; ++j) acc[j] = (float)r0[j];
    }
    for (int k = beg + half; k < end; k += 2) {
        unsigned v = edata[k];
        int s = (int)(v & 0x3FFFFu);
        float w = (float)(v >> 18) * QINV;
        h4 r = *reinterpret_cast<const h4*>(g + (size_t)s * 16 + sub * 4);
#pragma unroll
        for (int j = 0; j < 4; ++j) acc[j] = fmaf((float)r[j], w, acc[j]);
    }
#pragma unroll
    for (int j = 0; j < 4; ++j) acc[j] += __shfl_xor(acc[j], 4, 64);
    float dv = dinv[i];
#pragma unroll
    for (int j = 0; j < 4; ++j) acc[j] *= dv;  // raw3 slice (halves identical)
    // rebuild full raw3[16] across the feature quad
    float pv[8], raw[16];
    int oo = (sub & 1) * 4;
#pragma unroll
    for (int j = 0; j < 4; ++j) {
        float o1 = __shfl_xor(acc[j], 1, 64);
        pv[oo + j] = acc[j];
        pv[(oo ^ 4) + j] = o1;
    }
    int pb = (sub & 2) * 4;
#pragma unroll
    for (int j = 0; j < 8; ++j) {
        float o2v = __shfl_xor(pv[j], 2, 64);
        raw[pb + j] = pv[j];
        raw[(pb ^ 8) + j] = o2v;
    }
    // dense 16->32 + head projection; lane (half*4+sub) handles o = lane8*4 .. +3
    int lane8 = half * 4 + sub;
    float p0 = (lane8 == 0) ? bfs[0] : 0.0f;
    float p1 = (lane8 == 0) ? bfs[1] : 0.0f;
    float p2 = (lane8 == 0) ? bfs[2] : 0.0f;
    float q0 = 0.0f, q1 = 0.0f, q2 = 0.0f;
#pragma unroll
    for (int jo = 0; jo < 4; ++jo) {
        int o = lane8 * 4 + jo;
        float h = bs[o];
#pragma unroll
        for (int k = 0; k < 16; ++k) h = fmaf(raw[k], Ws[k * 32 + o], h);
        h = fmaxf(h, 0.0f);
        p0 = fmaf(h, wfs[o * 3 + 0], p0);
        p1 = fmaf(h, wfs[o * 3 + 1], p1);
        p2 = fmaf(h, wfs[o * 3 + 2], p2);
        q0 = fmaf(h, wfs[(32 + o) * 3 + 0], q0);
        q1 = fmaf(h, wfs[(32 + o) * 3 + 1], q1);
        q2 = fmaf(h, wfs[(32 + o) * 3 + 2], q2);
    }
    // reduce across all 8 lanes of the node group (true reduction now)
    p0 += __shfl_xor(p0, 1, 64); p0 += __shfl_xor(p0, 2, 64); p0 += __shfl_xor(p0, 4, 64);
    p1 += __shfl_xor(p1, 1, 64); p1 += __shfl_xor(p1, 2, 64); p1 += __shfl_xor(p1, 4, 64);
    p2 += __shfl_xor(p2, 1, 64); p2 += __shfl_xor(p2, 2, 64); p2 += __shfl_xor(p2, 4, 64);
    q0 += __shfl_xor(q0, 1, 64); q0 += __shfl_xor(q0, 2, 64); q0 += __shfl_xor(q0, 4, 64);
    q1 += __shfl_xor(q1, 1, 64); q1 += __shfl_xor(q1, 2, 64); q1 += __shfl_xor(q1, 4, 64);
    q2 += __shfl_xor(q2, 1, 64); q2 += __shfl_xor(q2, 2, 64); q2 += __shfl_xor(q2, 4, 64);
    if (lane8 == 0) {
        h8 o8;
        o8[0] = (_Float16)p0; o8[1] = (_Float16)p1; o8[2] = (_Float16)p2; o8[3] = (_Float16)0.0f;
        o8[4] = (_Float16)q0; o8[5] = (_Float16)q1; o8[6] = (_Float16)q2; o8[7] = (_Float16)0.0f;
        *reinterpret_cast<h8*>(pqh + (size_t)i * 8) = o8;
    }
}

// ---- head: out[e] = p[a] + q[b]   (fp16 pq table, fp32 out)
__global__ void head_kernel(const int* __restrict__ w2b, const _Float16* __restrict__ pqh,
                            float* __restrict__ out, int nw) {
    int e = blockIdx.x * blockDim.x + threadIdx.x;
    if (e >= nw) return;
    int a = w2b[e];
    int b = w2b[(size_t)nw + e];
    h4 P = *reinterpret_cast<const h4*>(pqh + (size_t)a * 8);
    h4 Q = *reinterpret_cast<const h4*>(pqh + (size_t)b * 8 + 4);
    out[(size_t)e * 3 + 0] = (float)P[0] + (float)Q[0];
    out[(size_t)e * 3 + 1] = (float)P[1] + (float)Q[1];
    out[(size_t)e * 3 + 2] = (float)P[2] + (float)Q[2];
}

extern "C" void kernel_launch(void* const* d_in, const int* in_sizes, int n_in,
                              void* d_out, int out_size, void* d_ws, size_t ws_size,
                              hipStream_t stream) {
    const float* x   = (const float*)d_in[0];
    const int* eidx  = (const int*)d_in[1];
    const int* w2b   = (const int*)d_in[2];
    const float* ew  = (const float*)d_in[3];
    const float* W1  = (const float*)d_in[4];
    const float* b1  = (const float*)d_in[5];
    const float* W2  = (const float*)d_in[6];
    const float* b2  = (const float*)d_in[7];
    const float* W3  = (const float*)d_in[8];
    const float* b3  = (const float*)d_in[9];
    const float* Wl1 = (const float*)d_in[10];
    const float* bl1 = (const float*)d_in[11];
    const float* Wl2 = (const float*)d_in[12];
    const float* bl2 = (const float*)d_in[13];
    float* out = (float*)d_out;

    const int n  = in_sizes[0] / 7;   // 200000
    const int ne = in_sizes[1] / 2;   // 4000000
    const int nw = in_sizes[2] / 2;   // 2000000
    const int* src = eidx;
    const int* dst = eidx + ne;

    const int nbins = (n + NPB - 1) / NPB;    // 782
    const int chunk = (ne + NB1 - 1) / NB1;   // 5209

    // ---- workspace layout (4B words) ----
    float*     ws      = (float*)d_ws;
    float*     dinv    = ws;                                    // n
    int*       C       = (int*)(ws + n);                        // n+1 (+pad)
    unsigned*  edata   = (unsigned*)(ws + 2 * (size_t)n + 16);  // ne
    int*       bh      = (int*)(edata + ne);                    // nbins*NB1
    int*       bintot  = bh + (size_t)nbins * NB1;              // MAXBINS
    int*       binbase = bintot + MAXBINS;                      // MAXBINS
    _Float16*  g0      = (_Float16*)(binbase + MAXBINS);        // 8n halves (2n words)
    float*     bregion = (float*)(g0 + (size_t)n * 8);          // 2*ne words
    unsigned long long* b64 = (unsigned long long*)bregion;     // ne u64 (dead after p2)
    _Float16*  g1      = (_Float16*)bregion;                    // 8n halves  } alias
    _Float16*  g2      = (_Float16*)(bregion + 4 * (size_t)n);  // 16n halves } into
    _Float16*  pqh     = (_Float16*)(bregion + 12 * (size_t)n); // 8n halves  } b64

    const int Bl = 256;
    auto blks = [&](long long t) { return (int)((t + Bl - 1) / Bl); };
    const int nb8 = blks((long long)n * 8);  // 8 lanes per node

    // 1. CSR build (counting sort; tile-sorted write-combined scatter)
    p1a_hist<<<NB1, Bl, 0, stream>>>(dst, bh, ne, nbins, chunk);
    s1_scan<<<nbins, Bl, 0, stream>>>(bh, bintot);
    s2_scan<<<1, 1024, 0, stream>>>(bintot, binbase, nbins, ne);
    p1b_scatter<<<NB1, Bl, 0, stream>>>(src, dst, ew, bh, binbase, b64, ne, nbins, chunk);
    p2_build<<<nbins, Bl, 0, stream>>>(b64, binbase, edata, C, dinv, x, W1, g0, n, ne, nbins);

    // 2. three fused 8-lane-per-node gather layers
    gather1_kernel<<<nb8, Bl, 0, stream>>>(g0, dinv, C, edata, b1, g1, n);
    gather2_kernel<<<nb8, Bl, 0, stream>>>(g1, dinv, C, edata, W2, b2, g2, n);
    gather3_kernel<<<nb8, Bl, 0, stream>>>(g2, dinv, C, edata, W3, b3,
                                           Wl1, bl1, Wl2, bl2, pqh, n);

    // 3. head
    head_kernel<<<blks(nw), Bl, 0, stream>>>(w2b, pqh, out, nw);
}

// Round 13
// 367.093 us; speedup vs baseline: 2.9186x; 1.0815x over previous
//
#include <hip/hip_runtime.h>
#include <hip/hip_bf16.h>
#include <hip/hip_fp16.h>

// GCN 3-layer + edge-MLP head. R13 = R12 + batch-4 software-pipelined gather
// loops: 4 independent edata loads, then 4 independent row loads, then FMAs
// (4x memory-level parallelism per thread; the serial edata->row chain was the
// R12 limiter: 26G line-fetches/s << L2/HBM ceilings, VALUBusy only 55%).
// R10 lesson: LDS-atomic bin gather is 2.6x worse than register accumulation.
//
// Build: bin = dst>>8. p1a per-(bin,block) LDS histogram; s1/s2 scans; p1b LDS
// tile-sort + write-combined flush of u64(src|q<<18|dl<<32|bin<<40); p2 per-bin
// CSR finalize (node-sorted 4B edata + C + dinv + fused g0 = dinv(.)(x@W1) fp16).
// gathers: 8 lanes/node (4 feat-split x 2 edge-half), fp16 tables, fp32 accum,
// denses fused into epilogues split across all 8 lanes.
// head: out[e] = p[a] + q[b] from fp16 pq table.

#define NB1 768
#define NPB 256
#define MAXBINS 1024
#define TILE 4096
#define QS 16384.0f
#define QINV (1.0f / 16384.0f)

typedef _Float16 h2 __attribute__((ext_vector_type(2)));
typedef _Float16 h4 __attribute__((ext_vector_type(4)));
typedef _Float16 h8 __attribute__((ext_vector_type(8)));

__device__ __forceinline__ float sigmoidf_(float x) {
    return 1.0f / (1.0f + __expf(-x));
}

// ---- P1a: per-(bin,block) histogram via LDS
__global__ void p1a_hist(const int* __restrict__ dst, int* __restrict__ bh,
                         int ne, int nbins, int chunk) {
    __shared__ int h[MAXBINS];
    for (int k = threadIdx.x; k < nbins; k += 256) h[k] = 0;
    __syncthreads();
    int base = blockIdx.x * chunk;
    int end = min(base + chunk, ne);
    for (int e = base + threadIdx.x; e < end; e += 256)
        atomicAdd(&h[dst[e] >> 8], 1);
    __syncthreads();
    for (int k = threadIdx.x; k < nbins; k += 256)
        bh[(size_t)k * NB1 + blockIdx.x] = h[k];
}

// ---- S1: per-bin exclusive scan over NB1 block counts + bin totals
__global__ void s1_scan(int* __restrict__ bh, int* __restrict__ bintot) {
    __shared__ int sums[256];
    constexpr int W = NB1 / 256;
    int* row = bh + (size_t)blockIdx.x * NB1;
    int v[W];
    int s = 0;
#pragma unroll
    for (int j = 0; j < W; ++j) { v[j] = row[threadIdx.x * W + j]; s += v[j]; }
    sums[threadIdx.x] = s;
    __syncthreads();
    for (int o = 1; o < 256; o <<= 1) {
        int t = (threadIdx.x >= o) ? sums[threadIdx.x - o] : 0;
        __syncthreads();
        sums[threadIdx.x] += t;
        __syncthreads();
    }
    int excl = sums[threadIdx.x] - s;
#pragma unroll
    for (int j = 0; j < W; ++j) { row[threadIdx.x * W + j] = excl; excl += v[j]; }
    if (threadIdx.x == 255) bintot[blockIdx.x] = sums[255];
}

// ---- S2: exclusive scan of bin totals -> binbase
__global__ void s2_scan(const int* __restrict__ bintot, int* __restrict__ binbase,
                        int nbins, int ne) {
    __shared__ int tmp[1024];
    int tid = threadIdx.x;
    int v = (tid < nbins) ? bintot[tid] : 0;
    tmp[tid] = v;
    __syncthreads();
    for (int o = 1; o < 1024; o <<= 1) {
        int t = (tid >= o) ? tmp[tid - o] : 0;
        __syncthreads();
        tmp[tid] += t;
        __syncthreads();
    }
    if (tid < nbins) binbase[tid] = tmp[tid] - v;
    if (tid == 0) binbase[nbins] = ne;
}

// ---- P1b: LDS tile-sort + coalesced flush into bin-grouped u64 array
__global__ void p1b_scatter(const int* __restrict__ src, const int* __restrict__ dst,
                            const float* __restrict__ ew, const int* __restrict__ bh,
                            const int* __restrict__ binbase,
                            unsigned long long* __restrict__ b64,
                            int ne, int nbins, int chunk) {
    __shared__ unsigned long long stage[TILE];
    __shared__ int hist[MAXBINS];
    __shared__ int boff[MAXBINS];
    __shared__ int cur[MAXBINS];
    __shared__ int ssum[256];
    constexpr int MPT = TILE / 256;
    for (int k = threadIdx.x; k < nbins; k += 256)
        cur[k] = binbase[k] + bh[(size_t)k * NB1 + blockIdx.x];
    int base = blockIdx.x * chunk;
    int endb = min(base + chunk, ne);
    for (int t0 = base; t0 < endb; t0 += TILE) {
        int cnt = min(TILE, endb - t0);
        for (int k = threadIdx.x; k < nbins; k += 256) hist[k] = 0;
        __syncthreads();
        unsigned long long ent[MPT];
        int m = 0;
        for (int j = threadIdx.x; j < cnt; j += 256) {
            int e = t0 + j;
            int d = dst[e];
            float w = sigmoidf_(ew[e]);
            int q = (int)fminf(w * QS + 0.5f, 16383.0f);
            int b = d >> 8;
            ent[m++] = (unsigned long long)((unsigned)src[e] | ((unsigned)q << 18))
                     | ((unsigned long long)(d & 255) << 32)
                     | ((unsigned long long)b << 40);
            atomicAdd(&hist[b], 1);
        }
        __syncthreads();
        int w0 = threadIdx.x * 4;
        int lv[4];
        int ls = 0;
#pragma unroll
        for (int j = 0; j < 4; ++j) {
            int idx = w0 + j;
            lv[j] = (idx < nbins) ? hist[idx] : 0;
            ls += lv[j];
        }
        ssum[threadIdx.x] = ls;
        __syncthreads();
        for (int o = 1; o < 256; o <<= 1) {
            int t = (threadIdx.x >= o) ? ssum[threadIdx.x - o] : 0;
            __syncthreads();
            ssum[threadIdx.x] += t;
            __syncthreads();
        }
        int excl = ssum[threadIdx.x] - ls;
#pragma unroll
        for (int j = 0; j < 4; ++j) {
            int idx = w0 + j;
            if (idx < nbins) { boff[idx] = excl; excl += lv[j]; }
        }
        __syncthreads();
        for (int k = threadIdx.x; k < nbins; k += 256) hist[k] = 0;
        __syncthreads();
        for (int j = 0; j < m; ++j) {
            int b = (int)(ent[j] >> 40);
            int p = boff[b] + atomicAdd(&hist[b], 1);
            stage[p] = ent[j];
        }
        __syncthreads();
        for (int j = threadIdx.x; j < cnt; j += 256) {
            unsigned long long v = stage[j];
            int b = (int)(v >> 40);
            b64[cur[b] + (j - boff[b])] = v;
        }
        __syncthreads();
        for (int k = threadIdx.x; k < nbins; k += 256) cur[k] += hist[k];
        __syncthreads();
    }
}

// ---- P2: per-bin CSR finalize + dinv + fused g0 = dinv (.) (x @ W1) fp16
__global__ void p2_build(const unsigned long long* __restrict__ b64,
                         const int* __restrict__ binbase, unsigned* __restrict__ edata,
                         int* __restrict__ C, float* __restrict__ dinv,
                         const float* __restrict__ x, const float* __restrict__ W1,
                         _Float16* __restrict__ g0, int n, int ne, int nbins) {
    __shared__ int cnt[NPB];
    __shared__ int rs[NPB];
    __shared__ int curs[NPB];
    __shared__ unsigned qsum[NPB];
    __shared__ float Ws[56];
    if (threadIdx.x < 56) Ws[threadIdx.x] = W1[threadIdx.x];
    int b = blockIdx.x;
    int E0 = binbase[b], E1 = binbase[b + 1];
    cnt[threadIdx.x] = 0;
    qsum[threadIdx.x] = 0;
    __syncthreads();
    for (int k = E0 + threadIdx.x; k < E1; k += 256)
        atomicAdd(&cnt[(int)((b64[k] >> 32) & 0xFF)], 1);
    __syncthreads();
    int v = cnt[threadIdx.x];
    rs[threadIdx.x] = v;
    __syncthreads();
    for (int o = 1; o < NPB; o <<= 1) {
        int t = (threadIdx.x >= o) ? rs[threadIdx.x - o] : 0;
        __syncthreads();
        rs[threadIdx.x] += t;
        __syncthreads();
    }
    int excl = rs[threadIdx.x] - v;
    curs[threadIdx.x] = E0 + excl;
    int node = b * NPB + threadIdx.x;
    if (node < n) C[node] = E0 + excl;
    if (b == 0 && threadIdx.x == 0) C[n] = ne;
    __syncthreads();
    for (int k = E0 + threadIdx.x; k < E1; k += 256) {
        unsigned long long e64 = b64[k];
        int dl = (int)((e64 >> 32) & 0xFF);
        int pos = atomicAdd(&curs[dl], 1);
        edata[pos] = (unsigned)(e64 & 0xFFFFFFFFu);
        atomicAdd(&qsum[dl], (unsigned)((e64 >> 18) & 0x3FFFu));
    }
    __syncthreads();
    if (node < n) {
        float dv = rsqrtf((float)qsum[threadIdx.x] * QINV + 1.0f);
        dinv[node] = dv;
        float xi[7];
#pragma unroll
        for (int k = 0; k < 7; ++k) xi[k] = x[(size_t)node * 7 + k];
        h8 r;
#pragma unroll
        for (int o = 0; o < 8; ++o) {
            float acc = 0.0f;
#pragma unroll
            for (int k = 0; k < 7; ++k) acc = fmaf(xi[k], Ws[k * 8 + o], acc);
            r[o] = (_Float16)(acc * dv);
        }
        *reinterpret_cast<h8*>(g0 + (size_t)node * 8) = r;
    }
}

// ---- gather1 (8 lanes/node; batch-4 pipelined edge loop)
__global__ void gather1_kernel(const _Float16* __restrict__ g, const float* __restrict__ dinv,
                               const int* __restrict__ C, const unsigned* __restrict__ edata,
                               const float* __restrict__ b1, _Float16* __restrict__ out, int n) {
    __shared__ float bs[8];
    if (threadIdx.x < 8) bs[threadIdx.x] = b1[threadIdx.x];
    __syncthreads();
    long long t = (long long)blockIdx.x * blockDim.x + threadIdx.x;
    int i = (int)(t >> 3);
    int sub = (int)(t & 3);
    int half = (int)((t >> 2) & 1);
    if (i >= n) return;
    int beg = C[i], end = C[i + 1];
    const _Float16* gb = g + sub * 2;
    float a0 = 0.0f, a1 = 0.0f;
    if (half == 0) {
        h2 r0 = *reinterpret_cast<const h2*>(gb + (size_t)i * 8);
        a0 = (float)r0[0]; a1 = (float)r0[1];
    }
    int k = beg + half;
    for (; k + 6 < end; k += 8) {
        unsigned v0 = edata[k];
        unsigned v1 = edata[k + 2];
        unsigned v2 = edata[k + 4];
        unsigned v3 = edata[k + 6];
        h2 r0 = *reinterpret_cast<const h2*>(gb + (size_t)(v0 & 0x3FFFFu) * 8);
        h2 r1 = *reinterpret_cast<const h2*>(gb + (size_t)(v1 & 0x3FFFFu) * 8);
        h2 r2 = *reinterpret_cast<const h2*>(gb + (size_t)(v2 & 0x3FFFFu) * 8);
        h2 r3 = *reinterpret_cast<const h2*>(gb + (size_t)(v3 & 0x3FFFFu) * 8);
        float w0 = (float)(v0 >> 18) * QINV;
        float w1 = (float)(v1 >> 18) * QINV;
        float w2 = (float)(v2 >> 18) * QINV;
        float w3 = (float)(v3 >> 18) * QINV;
        a0 = fmaf((float)r0[0], w0, a0); a1 = fmaf((float)r0[1], w0, a1);
        a0 = fmaf((float)r1[0], w1, a0); a1 = fmaf((float)r1[1], w1, a1);
        a0 = fmaf((float)r2[0], w2, a0); a1 = fmaf((float)r2[1], w2, a1);
        a0 = fmaf((float)r3[0], w3, a0); a1 = fmaf((float)r3[1], w3, a1);
    }
    for (; k < end; k += 2) {
        unsigned v = edata[k];
        float w = (float)(v >> 18) * QINV;
        h2 r = *reinterpret_cast<const h2*>(gb + (size_t)(v & 0x3FFFFu) * 8);
        a0 = fmaf((float)r[0], w, a0);
        a1 = fmaf((float)r[1], w, a1);
    }
    a0 += __shfl_xor(a0, 4, 64);
    a1 += __shfl_xor(a1, 4, 64);
    if (half == 0) {
        float dv = dinv[i];
        h2 o2;
        o2[0] = (_Float16)(dv * fmaxf(dv * a0 + bs[sub * 2 + 0], 0.0f));
        o2[1] = (_Float16)(dv * fmaxf(dv * a1 + bs[sub * 2 + 1], 0.0f));
        *reinterpret_cast<h2*>(out + (size_t)i * 8 + sub * 2) = o2;
    }
}

// ---- gather2 (8 lanes/node; batch-4 loop) + fused dense 8->16 split 8 ways
__global__ void gather2_kernel(const _Float16* __restrict__ g, const float* __restrict__ dinv,
                               const int* __restrict__ C, const unsigned* __restrict__ edata,
                               const float* __restrict__ W2, const float* __restrict__ b2,
                               _Float16* __restrict__ out, int n) {
    __shared__ float Ws[128];
    __shared__ float bs[16];
    if (threadIdx.x < 128) Ws[threadIdx.x] = W2[threadIdx.x];
    if (threadIdx.x < 16) bs[threadIdx.x] = b2[threadIdx.x];
    __syncthreads();
    long long t = (long long)blockIdx.x * blockDim.x + threadIdx.x;
    int i = (int)(t >> 3);
    int sub = (int)(t & 3);
    int half = (int)((t >> 2) & 1);
    if (i >= n) return;
    int beg = C[i], end = C[i + 1];
    const _Float16* gb = g + sub * 2;
    float a0 = 0.0f, a1 = 0.0f;
    if (half == 0) {
        h2 r0 = *reinterpret_cast<const h2*>(gb + (size_t)i * 8);
        a0 = (float)r0[0]; a1 = (float)r0[1];
    }
    int k = beg + half;
    for (; k + 6 < end; k += 8) {
        unsigned v0 = edata[k];
        unsigned v1 = edata[k + 2];
        unsigned v2 = edata[k + 4];
        unsigned v3 = edata[k + 6];
        h2 r0 = *reinterpret_cast<const h2*>(gb + (size_t)(v0 & 0x3FFFFu) * 8);
        h2 r1 = *reinterpret_cast<const h2*>(gb + (size_t)(v1 & 0x3FFFFu) * 8);
        h2 r2 = *reinterpret_cast<const h2*>(gb + (size_t)(v2 & 0x3FFFFu) * 8);
        h2 r3 = *reinterpret_cast<const h2*>(gb + (size_t)(v3 & 0x3FFFFu) * 8);
        float w0 = (float)(v0 >> 18) * QINV;
        float w1 = (float)(v1 >> 18) * QINV;
        float w2 = (float)(v2 >> 18) * QINV;
        float w3 = (float)(v3 >> 18) * QINV;
        a0 = fmaf((float)r0[0], w0, a0); a1 = fmaf((float)r0[1], w0, a1);
        a0 = fmaf((float)r1[0], w1, a0); a1 = fmaf((float)r1[1], w1, a1);
        a0 = fmaf((float)r2[0], w2, a0); a1 = fmaf((float)r2[1], w2, a1);
        a0 = fmaf((float)r3[0], w3, a0); a1 = fmaf((float)r3[1], w3, a1);
    }
    for (; k < end; k += 2) {
        unsigned v = edata[k];
        float w = (float)(v >> 18) * QINV;
        h2 r = *reinterpret_cast<const h2*>(gb + (size_t)(v & 0x3FFFFu) * 8);
        a0 = fmaf((float)r[0], w, a0);
        a1 = fmaf((float)r[1], w, a1);
    }
    a0 += __shfl_xor(a0, 4, 64);
    a1 += __shfl_xor(a1, 4, 64);
    float dv = dinv[i];
    float acc[2] = {a0 * dv, a1 * dv};  // raw2 slice (both halves identical)
    // rebuild full raw2[8] across the feature quad (lanes xor 1,2)
    float pv[4], raw[8];
    int oo = (sub & 1) * 2;
#pragma unroll
    for (int j = 0; j < 2; ++j) {
        float o1 = __shfl_xor(acc[j], 1, 64);
        pv[oo + j] = acc[j];
        pv[(oo ^ 2) + j] = o1;
    }
    int pb = (sub & 2) * 2;
#pragma unroll
    for (int j = 0; j < 4; ++j) {
        float o2v = __shfl_xor(pv[j], 2, 64);
        raw[pb + j] = pv[j];
        raw[(pb ^ 4) + j] = o2v;
    }
    // dense: lane (half*4+sub) computes outputs o = lane8*2 .. +1 (2 of 16)
    int lane8 = half * 4 + sub;
    h2 o2;
#pragma unroll
    for (int jo = 0; jo < 2; ++jo) {
        int o = lane8 * 2 + jo;
        float h = bs[o];
#pragma unroll
        for (int k2 = 0; k2 < 8; ++k2) h = fmaf(raw[k2], Ws[k2 * 16 + o], h);
        o2[jo] = (_Float16)(dv * fmaxf(h, 0.0f));
    }
    *reinterpret_cast<h2*>(out + (size_t)i * 16 + lane8 * 2) = o2;
}

// ---- gather3 (8 lanes/node; batch-4 loop) + fused dense 16->32 + head proj
__global__ void gather3_kernel(const _Float16* __restrict__ g, const float* __restrict__ dinv,
                               const int* __restrict__ C, const unsigned* __restrict__ edata,
                               const float* __restrict__ W3, const float* __restrict__ b3,
                               const float* __restrict__ Wl1, const float* __restrict__ bl1,
                               const float* __restrict__ Wl2, const float* __restrict__ bl2,
                               _Float16* __restrict__ pqh, int n) {
    __shared__ float Ws[512];
    __shared__ float bs[32];
    __shared__ float wfs[192];
    __shared__ float bfs[3];
    for (int k = threadIdx.x; k < 512; k += 256) Ws[k] = W3[k];
    if (threadIdx.x < 32) bs[threadIdx.x] = b3[threadIdx.x];
    if (threadIdx.x < 192) {
        int f = threadIdx.x / 3, j = threadIdx.x % 3;
        float acc = 0.0f;
#pragma unroll
        for (int k = 0; k < 4; ++k) acc = fmaf(Wl1[f * 4 + k], Wl2[k * 3 + j], acc);
        wfs[threadIdx.x] = acc;
    }
    if (threadIdx.x < 3) {
        float acc = bl2[threadIdx.x];
#pragma unroll
        for (int k = 0; k < 4; ++k) acc = fmaf(bl1[k], Wl2[k * 3 + threadIdx.x], acc);
        bfs[threadIdx.x] = acc;
    }
    __syncthreads();
    long long t = (long long)blockIdx.x * blockDim.x + threadIdx.x;
    int i = (int)(t >> 3);
    int sub = (int)(t & 3);
    int half = (int)((t >> 2) & 1);
    if (i >= n) return;
    int beg = C[i], end = C[i + 1];
    const _Float16* gb = g + sub * 4;
    float acc[4] = {0.0f, 0.0f, 0.0f, 0.0f};
    if (half == 0) {
        h4 r0 = *reinterpret_cast<const h4*>(gb + (size_t)i * 16);
#pragma unroll
        for (int j = 0; j < 4; ++j) acc[j] = (float)r0[j];
    }
    int k = beg + half;
    for (; k + 6 < end; k += 8) {
        unsigned v0 = edata[k];
        unsigned v1 = edata[k + 2];
        unsigned v2 = edata[k + 4];
        unsigned v3 = edata[k + 6];
        h4 r0 = *reinterpret_cast<const h4*>(gb + (size_t)(v0 & 0x3FFFFu) * 16);
        h4 r1 = *reinterpret_cast<const h4*>(gb + (size_t)(v1 & 0x3FFFFu) * 16);
        h4 r2 = *reinterpret_cast<const h4*>(gb + (size_t)(v2 & 0x3FFFFu) * 16);
        h4 r3 = *reinterpret_cast<const h4*>(gb + (size_t)(v3 & 0x3FFFFu) * 16);
        float w0 = (float)(v0 >> 18) * QINV;
        float w1 = (float)(v1 >> 18) * QINV;
        float w2 = (float)(v2 >> 18) * QINV;
        float w3 = (float)(v3 >> 18) * QINV;
#pragma unroll
        for (int j = 0; j < 4; ++j) acc[j] = fmaf((float)r0[j], w0, acc[j]);
#pragma unroll
        for (int j = 0; j < 4; ++j) acc[j] = fmaf((float)r1[j], w1, acc[j]);
#pragma unroll
        for (int j = 0; j < 4; ++j) acc[j] = fmaf((float)r2[j], w2, acc[j]);
#pragma unroll
        for (int j = 0; j < 4; ++j) acc[j] = fmaf((float)r3[j], w3, acc[j]);
    }
    for (; k < end; k += 2) {
        unsigned v = edata[k];
        float w = (float)(v >> 18) * QINV;
        h4 r = *reinterpret_cast<const h4*>(gb + (size_t)(v & 0x3FFFFu) * 16);
#pragma unroll
        for (int j = 0; j < 4; ++j) acc[j] = fmaf((float)r[j], w, acc[j]);
    }
#pragma unroll
    for (int j = 0; j < 4; ++j) acc[j] += __shfl_xor(acc[j], 4, 64);
    float dv = dinv[i];
#pragma unroll
    for (int j = 0; j < 4; ++j) acc[j] *= dv;  // raw3 slice (halves identical)
    // rebuild full raw3[16] across the feature quad
    float pv[8], raw[16];
    int oo = (sub & 1) * 4;
#pragma unroll
    for (int j = 0; j < 4; ++j) {
        float o1 = __shfl_xor(acc[j], 1, 64);
        pv[oo + j] = acc[j];
        pv[(oo ^ 4) + j] = o1;
    }
    int pb = (sub & 2) * 4;
#pragma unroll
    for (int j = 0; j < 8; ++j) {
        float o2v = __shfl_xor(pv[j], 2, 64);
        raw[pb + j] = pv[j];
        raw[(pb ^ 8) + j] = o2v;
    }
    // dense 16->32 + head projection; lane (half*4+sub) handles o = lane8*4 .. +3
    int lane8 = half * 4 + sub;
    float p0 = (lane8 == 0) ? bfs[0] : 0.0f;
    float p1 = (lane8 == 0) ? bfs[1] : 0.0f;
    float p2 = (lane8 == 0) ? bfs[2] : 0.0f;
    float q0 = 0.0f, q1 = 0.0f, q2 = 0.0f;
#pragma unroll
    for (int jo = 0; jo < 4; ++jo) {
        int o = lane8 * 4 + jo;
        float h = bs[o];
#pragma unroll
        for (int k2 = 0; k2 < 16; ++k2) h = fmaf(raw[k2], Ws[k2 * 32 + o], h);
        h = fmaxf(h, 0.0f);
        p0 = fmaf(h, wfs[o * 3 + 0], p0);
        p1 = fmaf(h, wfs[o * 3 + 1], p1);
        p2 = fmaf(h, wfs[o * 3 + 2], p2);
        q0 = fmaf(h, wfs[(32 + o) * 3 + 0], q0);
        q1 = fmaf(h, wfs[(32 + o) * 3 + 1], q1);
        q2 = fmaf(h, wfs[(32 + o) * 3 + 2], q2);
    }
    // reduce across all 8 lanes of the node group
    p0 += __shfl_xor(p0, 1, 64); p0 += __shfl_xor(p0, 2, 64); p0 += __shfl_xor(p0, 4, 64);
    p1 += __shfl_xor(p1, 1, 64); p1 += __shfl_xor(p1, 2, 64); p1 += __shfl_xor(p1, 4, 64);
    p2 += __shfl_xor(p2, 1, 64); p2 += __shfl_xor(p2, 2, 64); p2 += __shfl_xor(p2, 4, 64);
    q0 += __shfl_xor(q0, 1, 64); q0 += __shfl_xor(q0, 2, 64); q0 += __shfl_xor(q0, 4, 64);
    q1 += __shfl_xor(q1, 1, 64); q1 += __shfl_xor(q1, 2, 64); q1 += __shfl_xor(q1, 4, 64);
    q2 += __shfl_xor(q2, 1, 64); q2 += __shfl_xor(q2, 2, 64); q2 += __shfl_xor(q2, 4, 64);
    if (lane8 == 0) {
        h8 o8;
        o8[0] = (_Float16)p0; o8[1] = (_Float16)p1; o8[2] = (_Float16)p2; o8[3] = (_Float16)0.0f;
        o8[4] = (_Float16)q0; o8[5] = (_Float16)q1; o8[6] = (_Float16)q2; o8[7] = (_Float16)0.0f;
        *reinterpret_cast<h8*>(pqh + (size_t)i * 8) = o8;
    }
}

// ---- head: out[e] = p[a] + q[b]   (fp16 pq table, fp32 out)
__global__ void head_kernel(const int* __restrict__ w2b, const _Float16* __restrict__ pqh,
                            float* __restrict__ out, int nw) {
    int e = blockIdx.x * blockDim.x + threadIdx.x;
    if (e >= nw) return;
    int a = w2b[e];
    int b = w2b[(size_t)nw + e];
    h4 P = *reinterpret_cast<const h4*>(pqh + (size_t)a * 8);
    h4 Q = *reinterpret_cast<const h4*>(pqh + (size_t)b * 8 + 4);
    out[(size_t)e * 3 + 0] = (float)P[0] + (float)Q[0];
    out[(size_t)e * 3 + 1] = (float)P[1] + (float)Q[1];
    out[(size_t)e * 3 + 2] = (float)P[2] + (float)Q[2];
}

extern "C" void kernel_launch(void* const* d_in, const int* in_sizes, int n_in,
                              void* d_out, int out_size, void* d_ws, size_t ws_size,
                              hipStream_t stream) {
    const float* x   = (const float*)d_in[0];
    const int* eidx  = (const int*)d_in[1];
    const int* w2b   = (const int*)d_in[2];
    const float* ew  = (const float*)d_in[3];
    const float* W1  = (const float*)d_in[4];
    const float* b1  = (const float*)d_in[5];
    const float* W2  = (const float*)d_in[6];
    const float* b2  = (const float*)d_in[7];
    const float* W3  = (const float*)d_in[8];
    const float* b3  = (const float*)d_in[9];
    const float* Wl1 = (const float*)d_in[10];
    const float* bl1 = (const float*)d_in[11];
    const float* Wl2 = (const float*)d_in[12];
    const float* bl2 = (const float*)d_in[13];
    float* out = (float*)d_out;

    const int n  = in_sizes[0] / 7;   // 200000
    const int ne = in_sizes[1] / 2;   // 4000000
    const int nw = in_sizes[2] / 2;   // 2000000
    const int* src = eidx;
    const int* dst = eidx + ne;

    const int nbins = (n + NPB - 1) / NPB;    // 782
    const int chunk = (ne + NB1 - 1) / NB1;   // 5209

    // ---- workspace layout (4B words) ----
    float*     ws      = (float*)d_ws;
    float*     dinv    = ws;                                    // n
    int*       C       = (int*)(ws + n);                        // n+1 (+pad)
    unsigned*  edata   = (unsigned*)(ws + 2 * (size_t)n + 16);  // ne
    int*       bh      = (int*)(edata + ne);                    // nbins*NB1
    int*       bintot  = bh + (size_t)nbins * NB1;              // MAXBINS
    int*       binbase = bintot + MAXBINS;                      // MAXBINS
    _Float16*  g0      = (_Float16*)(binbase + MAXBINS);        // 8n halves (2n words)
    float*     bregion = (float*)(g0 + (size_t)n * 8);          // 2*ne words
    unsigned long long* b64 = (unsigned long long*)bregion;     // ne u64 (dead after p2)
    _Float16*  g1      = (_Float16*)bregion;                    // 8n halves  } alias
    _Float16*  g2      = (_Float16*)(bregion + 4 * (size_t)n);  // 16n halves } into
    _Float16*  pqh     = (_Float16*)(bregion + 12 * (size_t)n); // 8n halves  } b64

    const int Bl = 256;
    auto blks = [&](long long t) { return (int)((t + Bl - 1) / Bl); };
    const int nb8 = blks((long long)n * 8);  // 8 lanes per node

    // 1. CSR build (counting sort; tile-sorted write-combined scatter)
    p1a_hist<<<NB1, Bl, 0, stream>>>(dst, bh, ne, nbins, chunk);
    s1_scan<<<nbins, Bl, 0, stream>>>(bh, bintot);
    s2_scan<<<1, 1024, 0, stream>>>(bintot, binbase, nbins, ne);
    p1b_scatter<<<NB1, Bl, 0, stream>>>(src, dst, ew, bh, binbase, b64, ne, nbins, chunk);
    p2_build<<<nbins, Bl, 0, stream>>>(b64, binbase, edata, C, dinv, x, W1, g0, n, ne, nbins);

    // 2. three fused 8-lane-per-node gather layers
    gather1_kernel<<<nb8, Bl, 0, stream>>>(g0, dinv, C, edata, b1, g1, n);
    gather2_kernel<<<nb8, Bl, 0, stream>>>(g1, dinv, C, edata, W2, b2, g2, n);
    gather3_kernel<<<nb8, Bl, 0, stream>>>(g2, dinv, C, edata, W3, b3,
                                           Wl1, bl1, Wl2, bl2, pqh, n);

    // 3. head
    head_kernel<<<blks(nw), Bl, 0, stream>>>(w2b, pqh, out, nw);
}